// Round 1
// 1199.914 us; speedup vs baseline: 1.1808x; 1.1808x over previous
//
#include <hip/hip_runtime.h>
#include <hip/hip_bf16.h>

#define DD 128
#define AA 5

typedef short short8 __attribute__((ext_vector_type(8)));
typedef float f32x4 __attribute__((ext_vector_type(4)));

static __device__ __forceinline__ unsigned short f2bf(float f) {
    union { float f; unsigned u; } v; v.f = f;
    unsigned r = (v.u + 0x7fff + ((v.u >> 16) & 1)) >> 16;
    return (unsigned short)r;
}

// ---------------- node precompute: node_x, p1, p2 ----------------
__global__ __launch_bounds__(256) void k_node_pre(
    const float* __restrict__ x, const float* __restrict__ naw, const float* __restrict__ nab,
    const float* __restrict__ nanchor, const float* __restrict__ eww,
    float* __restrict__ node_x, float* __restrict__ p1, float* __restrict__ p2, int N)
{
    int wave = threadIdx.x >> 6;
    int lane = threadIdx.x & 63;
    int u = blockIdx.x * 4 + wave;
    if (u >= N) return;
    int d0 = lane * 2;
    float2 xv = *(const float2*)(x + (size_t)u * DD + d0);
    float nl[AA], a1[AA], a2[AA];
#pragma unroll
    for (int a = 0; a < AA; a++) {
        nl[a] = xv.x * naw[d0 * AA + a] + xv.y * naw[(d0 + 1) * AA + a];
        a1[a] = xv.x * eww[d0 * AA + a] + xv.y * eww[(d0 + 1) * AA + a];
        a2[a] = xv.x * eww[(DD + d0) * AA + a] + xv.y * eww[(DD + d0 + 1) * AA + a];
    }
#pragma unroll
    for (int off = 32; off >= 1; off >>= 1) {
#pragma unroll
        for (int a = 0; a < AA; a++) {
            nl[a] += __shfl_xor(nl[a], off, 64);
            a1[a] += __shfl_xor(a1[a], off, 64);
            a2[a] += __shfl_xor(a2[a], off, 64);
        }
    }
    float m = -1e30f;
#pragma unroll
    for (int a = 0; a < AA; a++) { nl[a] += nab[a]; m = fmaxf(m, nl[a]); }
    float ssum = 0.f;
#pragma unroll
    for (int a = 0; a < AA; a++) { nl[a] = __expf(nl[a] - m); ssum += nl[a]; }
    float inv = 1.0f / ssum;
    float2 o = xv;
#pragma unroll
    for (int a = 0; a < AA; a++) {
        float wgt = nl[a] * inv;
        o.x += wgt * nanchor[a * DD + d0];
        o.y += wgt * nanchor[a * DD + d0 + 1];
    }
    *(float2*)(node_x + (size_t)u * DD + d0) = o;
    if (lane == 0) {
#pragma unroll
        for (int a = 0; a < AA; a++) { p1[u * 8 + a] = a1[a]; p2[u * 8 + a] = a2[a]; }
    }
}

// ---------------- edge kernel: softmax coeffs -> dense store (NO atomics) ----------------
__global__ __launch_bounds__(256) void k_edge(
    const int* __restrict__ ei, const float* __restrict__ p1, const float* __restrict__ p2,
    const float* __restrict__ ewb, const float* __restrict__ eanchor,
    float* __restrict__ eprompt, float4* __restrict__ be4, float* __restrict__ be1, int E)
{
    __shared__ float be_sh[256][6];
    __shared__ float anc[AA][DD];
    int tid = threadIdx.x;
    for (int i = tid; i < AA * DD; i += 256) anc[i / DD][i % DD] = eanchor[i];
    int e0 = blockIdx.x * 256;
    int e = e0 + tid;
    if (e < E) {
        int s = ei[e], d = ei[E + e];
        float l[AA];
        float4 q1 = *(const float4*)(p1 + (size_t)s * 8);
        float  q1e = p1[(size_t)s * 8 + 4];
        float4 q2 = *(const float4*)(p2 + (size_t)d * 8);
        float  q2e = p2[(size_t)d * 8 + 4];
        l[0] = q1.x + q2.x; l[1] = q1.y + q2.y; l[2] = q1.z + q2.z; l[3] = q1.w + q2.w; l[4] = q1e + q2e;
        float m = -1e30f;
#pragma unroll
        for (int a = 0; a < AA; a++) {
            l[a] += ewb[a];
            l[a] = l[a] >= 0.f ? l[a] : 0.01f * l[a];
            m = fmaxf(m, l[a]);
        }
        float ssum = 0.f;
#pragma unroll
        for (int a = 0; a < AA; a++) { l[a] = __expf(l[a] - m); ssum += l[a]; }
        float inv = 1.f / ssum;
#pragma unroll
        for (int a = 0; a < AA; a++) {
            float b = l[a] * inv;
            be_sh[tid][a] = b;
        }
        float4 w;
        w.x = be_sh[tid][0]; w.y = be_sh[tid][1]; w.z = be_sh[tid][2]; w.w = be_sh[tid][3];
        be4[e] = w;
        be1[e] = be_sh[tid][4];
    }
    __syncthreads();
    int c4 = tid & 31;
    int r  = tid >> 5;
    int nvalid = min(256, E - e0);
    for (int j = r; j < nvalid; j += 8) {
        float4 v = {0.f, 0.f, 0.f, 0.f};
#pragma unroll
        for (int a = 0; a < AA; a++) {
            float b = be_sh[j][a];
            v.x += b * anc[a][c4 * 4 + 0];
            v.y += b * anc[a][c4 * 4 + 1];
            v.z += b * anc[a][c4 * 4 + 2];
            v.w += b * anc[a][c4 * 4 + 3];
        }
        *(float4*)(eprompt + (size_t)(e0 + j) * DD + c4 * 4) = v;
    }
}

// ---------------- z = node_x + (gathered coef) @ edge_anchor (in-place) ----------------
// 32 lanes per node: gather per-edge coeffs via edge-CSR, shfl-reduce, apply anchors.
__global__ __launch_bounds__(256) void k_z(
    const int* __restrict__ rowptr, const int* __restrict__ eadj,
    const float4* __restrict__ be4, const float* __restrict__ be1,
    const float* __restrict__ eanchor,
    float* __restrict__ z, int N)
{
    int tid = threadIdx.x;
    int l32 = tid & 31;
    int u = blockIdx.x * 8 + (tid >> 5);
    if (u >= N) return;
    int beg = rowptr[u], end = rowptr[u + 1];
    float c0 = 0.f, c1 = 0.f, c2 = 0.f, c3 = 0.f, c4v = 0.f;
    for (int j = beg + l32; j < end; j += 32) {
        int e = eadj[j];
        float4 v = be4[e];
        c0 += v.x; c1 += v.y; c2 += v.z; c3 += v.w;
        c4v += be1[e];
    }
#pragma unroll
    for (int off = 16; off >= 1; off >>= 1) {
        c0 += __shfl_xor(c0, off, 64);
        c1 += __shfl_xor(c1, off, 64);
        c2 += __shfl_xor(c2, off, 64);
        c3 += __shfl_xor(c3, off, 64);
        c4v += __shfl_xor(c4v, off, 64);
    }
    float4 v = *(float4*)(z + (size_t)u * DD + l32 * 4);
    const float4 a0 = *(const float4*)(eanchor + 0 * DD + l32 * 4);
    const float4 a1 = *(const float4*)(eanchor + 1 * DD + l32 * 4);
    const float4 a2 = *(const float4*)(eanchor + 2 * DD + l32 * 4);
    const float4 a3 = *(const float4*)(eanchor + 3 * DD + l32 * 4);
    const float4 a4 = *(const float4*)(eanchor + 4 * DD + l32 * 4);
    v.x += c0 * a0.x + c1 * a1.x + c2 * a2.x + c3 * a3.x + c4v * a4.x;
    v.y += c0 * a0.y + c1 * a1.y + c2 * a2.y + c3 * a3.y + c4v * a4.y;
    v.z += c0 * a0.z + c1 * a1.z + c2 * a2.z + c3 * a3.z + c4v * a4.z;
    v.w += c0 * a0.w + c1 * a1.w + c2 * a2.w + c3 * a3.w + c4v * a4.w;
    *(float4*)(z + (size_t)u * DD + l32 * 4) = v;
}

// ---------------- CSR build ----------------
__global__ __launch_bounds__(256) void k_deg(const int* __restrict__ ei, int* __restrict__ deg, int E)
{
    int e = blockIdx.x * 256 + threadIdx.x;
    if (e >= E) return;
    atomicAdd(&deg[ei[e]], 1);
    atomicAdd(&deg[ei[E + e]], 1);
}

__global__ __launch_bounds__(1024) void k_scan(
    const int* __restrict__ deg, int* __restrict__ rowptr, int* __restrict__ wp, int N, int total)
{
    __shared__ int sdata[1024];
    int t = threadIdx.x;
    int chunk = (N + 1023) >> 10;
    int start = t * chunk, end = min(start + chunk, N);
    int lsum = 0;
    for (int i = start; i < end; i++) lsum += deg[i];
    sdata[t] = lsum;
    __syncthreads();
    for (int off = 1; off < 1024; off <<= 1) {
        int v = (t >= off) ? sdata[t - off] : 0;
        __syncthreads();
        sdata[t] += v;
        __syncthreads();
    }
    int run = sdata[t] - lsum;
    for (int i = start; i < end; i++) { rowptr[i] = run; wp[i] = run; run += deg[i]; }
    if (t == 0) rowptr[N] = total;
}

__global__ __launch_bounds__(256) void k_fill(
    const int* __restrict__ ei, int* __restrict__ wp, int* __restrict__ adj,
    int* __restrict__ eadj, int E)
{
    int e = blockIdx.x * 256 + threadIdx.x;
    if (e >= E) return;
    int s = ei[e], d = ei[E + e];
    int ps = atomicAdd(&wp[s], 1); adj[ps] = d; eadj[ps] = e;
    int pd = atomicAdd(&wp[d], 1); adj[pd] = s; eadj[pd] = e;
}

// ---------------- wavelet step: fp32 out (optional) + bf16 mirror ----------------
__global__ __launch_bounds__(128) void k_wav(
    const int* __restrict__ rowptr, const int* __restrict__ adj,
    const float* __restrict__ yin, int in_stride,
    float* __restrict__ yout, int write_f32,
    unsigned short* __restrict__ bfout,   // comb_bf16 + chunk, stride 512
    float halfinvnorm, int N)
{
    int nl = threadIdx.x >> 5;
    int c4 = threadIdx.x & 31;
    int u = blockIdx.x * 4 + nl;
    if (u >= N) return;
    int beg = rowptr[u], end = rowptr[u + 1];
    float4 s0 = {0.f, 0.f, 0.f, 0.f}, s1 = {0.f, 0.f, 0.f, 0.f};
    int j = beg;
    for (; j + 1 < end; j += 2) {
        int n0 = adj[j], n1 = adj[j + 1];
        const float4 v0 = *(const float4*)(yin + (size_t)n0 * in_stride + c4 * 4);
        const float4 v1 = *(const float4*)(yin + (size_t)n1 * in_stride + c4 * 4);
        s0.x += v0.x; s0.y += v0.y; s0.z += v0.z; s0.w += v0.w;
        s1.x += v1.x; s1.y += v1.y; s1.z += v1.z; s1.w += v1.w;
    }
    if (j < end) {
        int n0 = adj[j];
        const float4 v0 = *(const float4*)(yin + (size_t)n0 * in_stride + c4 * 4);
        s0.x += v0.x; s0.y += v0.y; s0.z += v0.z; s0.w += v0.w;
    }
    const float4 self = *(const float4*)(yin + (size_t)u * in_stride + c4 * 4);
    float4 o;
    o.x = 0.5f * self.x + halfinvnorm * (s0.x + s1.x);
    o.y = 0.5f * self.y + halfinvnorm * (s0.y + s1.y);
    o.z = 0.5f * self.z + halfinvnorm * (s0.z + s1.z);
    o.w = 0.5f * self.w + halfinvnorm * (s0.w + s1.w);
    if (write_f32)
        *(float4*)(yout + (size_t)u * DD + c4 * 4) = o;
    ushort4 b;
    b.x = f2bf(o.x); b.y = f2bf(o.y); b.z = f2bf(o.z); b.w = f2bf(o.w);
    *(ushort4*)(bfout + (size_t)u * 512 + c4 * 4) = b;
}

// ---------------- weight conversion (transposed, bf16) ----------------
__global__ __launch_bounds__(256) void k_cvtw1(
    const float* __restrict__ w1, const float* __restrict__ scales,
    unsigned short* __restrict__ w1t)
{
    int t = blockIdx.x * 256 + threadIdx.x;
    if (t >= 512 * 256) return;
    int k = t >> 8, n = t & 255;
    w1t[n * 512 + k] = f2bf(w1[t] * scales[k >> 7]);
}

__global__ __launch_bounds__(256) void k_cvtw2(
    const float* __restrict__ w2, unsigned short* __restrict__ w2t)
{
    int t = blockIdx.x * 256 + threadIdx.x;
    if (t >= 256 * 128) return;
    int k = t >> 7, n = t & 127;
    w2t[n * 256 + k] = f2bf(w2[t]);
}

// ---------------- MFMA GEMM: out[N,NOUT] = A[N,K] @ Bt[NOUT,K]^T + bias ----------------
template<int K, bool RELU_BF16>
__global__ __launch_bounds__(256) void k_gemm(
    const unsigned short* __restrict__ A, const unsigned short* __restrict__ Bt,
    const float* __restrict__ bias, void* __restrict__ outp, int N, int NOUT)
{
    __shared__ short sA[128][40];
    __shared__ short sB[64][40];
    int tid = threadIdx.x;
    int r0 = blockIdx.x * 128;
    int n0 = blockIdx.y * 64;
    int lane = tid & 63;
    int w = tid >> 6;
    int quad = lane >> 4;
    int lrow = lane & 15;

    f32x4 acc[2][4];
#pragma unroll
    for (int s = 0; s < 2; s++)
#pragma unroll
        for (int t = 0; t < 4; t++) acc[s][t] = (f32x4){0.f, 0.f, 0.f, 0.f};

    for (int k0 = 0; k0 < K; k0 += 32) {
#pragma unroll
        for (int i = 0; i < 2; i++) {
            int c = tid + i * 256;
            int row = c >> 2, col = (c & 3) * 8;
            ushort4 v2[2];
            if (r0 + row < N) {
                const uint4 g = *(const uint4*)(A + (size_t)(r0 + row) * K + k0 + col);
                *(uint4*)v2 = g;
            } else {
                v2[0] = (ushort4){0,0,0,0}; v2[1] = (ushort4){0,0,0,0};
            }
            *(uint4*)&sA[row][col] = *(uint4*)v2;
        }
        {
            int row = tid >> 2, col = (tid & 3) * 8;
            const uint4 g = *(const uint4*)(Bt + (size_t)(n0 + row) * K + k0 + col);
            *(uint4*)&sB[row][col] = g;
        }
        __syncthreads();
        short8 afr[2], bfr[4];
#pragma unroll
        for (int s = 0; s < 2; s++)
            afr[s] = *(const short8*)&sA[w * 32 + s * 16 + lrow][quad * 8];
#pragma unroll
        for (int t = 0; t < 4; t++)
            bfr[t] = *(const short8*)&sB[t * 16 + lrow][quad * 8];
#pragma unroll
        for (int s = 0; s < 2; s++)
#pragma unroll
            for (int t = 0; t < 4; t++)
                acc[s][t] = __builtin_amdgcn_mfma_f32_16x16x32_bf16(afr[s], bfr[t], acc[s][t], 0, 0, 0);
        __syncthreads();
    }
#pragma unroll
    for (int s = 0; s < 2; s++) {
#pragma unroll
        for (int t = 0; t < 4; t++) {
            int col = n0 + t * 16 + lrow;
            float bb = bias[col];
#pragma unroll
            for (int r = 0; r < 4; r++) {
                int row = r0 + w * 32 + s * 16 + quad * 4 + r;
                if (row < N) {
                    float v = acc[s][t][r] + bb;
                    if (RELU_BF16) {
                        ((unsigned short*)outp)[(size_t)row * NOUT + col] = f2bf(fmaxf(v, 0.f));
                    } else {
                        ((float*)outp)[(size_t)row * NOUT + col] = v;
                    }
                }
            }
        }
    }
}

extern "C" void kernel_launch(void* const* d_in, const int* in_sizes, int n_in,
                              void* d_out, int out_size, void* d_ws, size_t ws_size,
                              hipStream_t stream)
{
    const float* x       = (const float*)d_in[0];
    const int*   ei      = (const int*)d_in[1];
    const float* nanchor = (const float*)d_in[2];
    const float* naw     = (const float*)d_in[3];
    const float* nab     = (const float*)d_in[4];
    const float* eanchor = (const float*)d_in[5];
    const float* eww     = (const float*)d_in[6];
    const float* ewb     = (const float*)d_in[7];
    const float* scales  = (const float*)d_in[8];
    const float* w1      = (const float*)d_in[9];
    const float* b1      = (const float*)d_in[10];
    const float* w2      = (const float*)d_in[11];
    const float* b2      = (const float*)d_in[12];

    int N = in_sizes[0] / DD;
    int E = in_sizes[1] / 2;
    float norm = (float)((double)E / (double)N + 1e-6);
    float hin = 0.5f / norm;

    char* wsb = (char*)d_ws;
    size_t off = 0;
    auto alloc = [&](size_t b) -> char* {
        char* p = wsb + off;
        off += (b + 255) & ~(size_t)255;
        return p;
    };
    float* node_x = (float*)alloc((size_t)N * DD * 4);   // becomes z after k_z
    float* yB     = (float*)alloc((size_t)N * DD * 4);
    float* yC     = (float*)alloc((size_t)N * DD * 4);
    float* p1     = (float*)alloc((size_t)N * 8 * 4);
    float* p2     = (float*)alloc((size_t)N * 8 * 4);
    unsigned short* comb_bf = (unsigned short*)alloc((size_t)N * 512 * 2);
    unsigned short* h_bf    = (unsigned short*)alloc((size_t)N * 256 * 2);
    unsigned short* w1t     = (unsigned short*)alloc((size_t)512 * 256 * 2);
    unsigned short* w2t     = (unsigned short*)alloc((size_t)256 * 128 * 2);
    int*   deg    = (int*)alloc((size_t)N * 4);
    int*   rowptr = (int*)alloc((size_t)(N + 1) * 4);
    int*   wp     = (int*)alloc((size_t)N * 4);
    int*   adj    = (int*)alloc((size_t)2 * E * 4);
    int*   eadj   = (int*)alloc((size_t)2 * E * 4);
    float4* be4   = (float4*)alloc((size_t)E * 16);
    float*  be1   = (float*)alloc((size_t)E * 4);

    float* out_final   = (float*)d_out;
    float* out_eprompt = out_final + (size_t)N * DD;

    hipMemsetAsync(deg, 0, (size_t)N * 4, stream);

    k_cvtw1<<<(512 * 256 + 255) / 256, 256, 0, stream>>>(w1, scales, w1t);
    k_cvtw2<<<(256 * 128 + 255) / 256, 256, 0, stream>>>(w2, w2t);

    k_node_pre<<<(N + 3) / 4, 256, 0, stream>>>(x, naw, nab, nanchor, eww, node_x, p1, p2, N);
    k_edge<<<(E + 255) / 256, 256, 0, stream>>>(ei, p1, p2, ewb, eanchor, out_eprompt, be4, be1, E);
    k_deg<<<(E + 255) / 256, 256, 0, stream>>>(ei, deg, E);
    k_scan<<<1, 1024, 0, stream>>>(deg, rowptr, wp, N, 2 * E);
    k_fill<<<(E + 255) / 256, 256, 0, stream>>>(ei, wp, adj, eadj, E);
    k_z<<<(N + 7) / 8, 256, 0, stream>>>(rowptr, eadj, be4, be1, eanchor, node_x, N);

    // 4 chained wavelet steps; bf16 mirror into comb_bf chunks, fp32 chain ping-pong
    k_wav<<<(N + 3) / 4, 128, 0, stream>>>(rowptr, adj, node_x, DD, yB, 1, comb_bf + 0,   hin, N);
    k_wav<<<(N + 3) / 4, 128, 0, stream>>>(rowptr, adj, yB,     DD, yC, 1, comb_bf + 128, hin, N);
    k_wav<<<(N + 3) / 4, 128, 0, stream>>>(rowptr, adj, yC,     DD, yB, 1, comb_bf + 256, hin, N);
    k_wav<<<(N + 3) / 4, 128, 0, stream>>>(rowptr, adj, yB,     DD, yC, 0, comb_bf + 384, hin, N);

    dim3 g1((N + 127) / 128, 4);
    k_gemm<512, true><<<g1, 256, 0, stream>>>(comb_bf, w1t, b1, h_bf, N, 256);
    dim3 g2((N + 127) / 128, 2);
    k_gemm<256, false><<<g2, 256, 0, stream>>>(h_bf, w2t, b2, out_final, N, 128);
}

// Round 2
// 1086.409 us; speedup vs baseline: 1.3042x; 1.1045x over previous
//
#include <hip/hip_runtime.h>
#include <hip/hip_bf16.h>

#define DD 128
#define AA 5

typedef short short8 __attribute__((ext_vector_type(8)));
typedef _Float16 half8 __attribute__((ext_vector_type(8)));
typedef float f32x4 __attribute__((ext_vector_type(4)));

static __device__ __forceinline__ unsigned short f2h(float f) {
    union { _Float16 h; unsigned short u; } v;
    v.h = (_Float16)f;
    return v.u;
}
static __device__ __forceinline__ float h2f(unsigned short u) {
    union { unsigned short u; _Float16 h; } v;
    v.u = u;
    return (float)v.h;
}

// ---------------- node precompute: node_x, p1, p2 ----------------
__global__ __launch_bounds__(256) void k_node_pre(
    const float* __restrict__ x, const float* __restrict__ naw, const float* __restrict__ nab,
    const float* __restrict__ nanchor, const float* __restrict__ eww,
    float* __restrict__ node_x, float* __restrict__ p1, float* __restrict__ p2, int N)
{
    int wave = threadIdx.x >> 6;
    int lane = threadIdx.x & 63;
    int u = blockIdx.x * 4 + wave;
    if (u >= N) return;
    int d0 = lane * 2;
    float2 xv = *(const float2*)(x + (size_t)u * DD + d0);
    float nl[AA], a1[AA], a2[AA];
#pragma unroll
    for (int a = 0; a < AA; a++) {
        nl[a] = xv.x * naw[d0 * AA + a] + xv.y * naw[(d0 + 1) * AA + a];
        a1[a] = xv.x * eww[d0 * AA + a] + xv.y * eww[(d0 + 1) * AA + a];
        a2[a] = xv.x * eww[(DD + d0) * AA + a] + xv.y * eww[(DD + d0 + 1) * AA + a];
    }
#pragma unroll
    for (int off = 32; off >= 1; off >>= 1) {
#pragma unroll
        for (int a = 0; a < AA; a++) {
            nl[a] += __shfl_xor(nl[a], off, 64);
            a1[a] += __shfl_xor(a1[a], off, 64);
            a2[a] += __shfl_xor(a2[a], off, 64);
        }
    }
    float m = -1e30f;
#pragma unroll
    for (int a = 0; a < AA; a++) { nl[a] += nab[a]; m = fmaxf(m, nl[a]); }
    float ssum = 0.f;
#pragma unroll
    for (int a = 0; a < AA; a++) { nl[a] = __expf(nl[a] - m); ssum += nl[a]; }
    float inv = 1.0f / ssum;
    float2 o = xv;
#pragma unroll
    for (int a = 0; a < AA; a++) {
        float wgt = nl[a] * inv;
        o.x += wgt * nanchor[a * DD + d0];
        o.y += wgt * nanchor[a * DD + d0 + 1];
    }
    *(float2*)(node_x + (size_t)u * DD + d0) = o;
    if (lane == 0) {
#pragma unroll
        for (int a = 0; a < AA; a++) { p1[u * 8 + a] = a1[a]; p2[u * 8 + a] = a2[a]; }
    }
}

// ---------------- edge kernel: softmax coeffs -> dense store + deg atomics ----------------
__global__ __launch_bounds__(256) void k_edge(
    const int* __restrict__ ei, const float* __restrict__ p1, const float* __restrict__ p2,
    const float* __restrict__ ewb, const float* __restrict__ eanchor,
    float* __restrict__ eprompt, float4* __restrict__ be4, float* __restrict__ be1,
    int* __restrict__ deg, int E)
{
    __shared__ float be_sh[256][6];
    __shared__ float anc[AA][DD];
    int tid = threadIdx.x;
    for (int i = tid; i < AA * DD; i += 256) anc[i / DD][i % DD] = eanchor[i];
    int e0 = blockIdx.x * 256;
    int e = e0 + tid;
    if (e < E) {
        int s = ei[e], d = ei[E + e];
        // fused degree count (fire-and-forget far atomics, hide under eprompt write BW)
        atomicAdd(&deg[s], 1);
        atomicAdd(&deg[d], 1);
        float l[AA];
        float4 q1 = *(const float4*)(p1 + (size_t)s * 8);
        float  q1e = p1[(size_t)s * 8 + 4];
        float4 q2 = *(const float4*)(p2 + (size_t)d * 8);
        float  q2e = p2[(size_t)d * 8 + 4];
        l[0] = q1.x + q2.x; l[1] = q1.y + q2.y; l[2] = q1.z + q2.z; l[3] = q1.w + q2.w; l[4] = q1e + q2e;
        float m = -1e30f;
#pragma unroll
        for (int a = 0; a < AA; a++) {
            l[a] += ewb[a];
            l[a] = l[a] >= 0.f ? l[a] : 0.01f * l[a];
            m = fmaxf(m, l[a]);
        }
        float ssum = 0.f;
#pragma unroll
        for (int a = 0; a < AA; a++) { l[a] = __expf(l[a] - m); ssum += l[a]; }
        float inv = 1.f / ssum;
#pragma unroll
        for (int a = 0; a < AA; a++) {
            float b = l[a] * inv;
            be_sh[tid][a] = b;
        }
        float4 w;
        w.x = be_sh[tid][0]; w.y = be_sh[tid][1]; w.z = be_sh[tid][2]; w.w = be_sh[tid][3];
        be4[e] = w;
        be1[e] = be_sh[tid][4];
    }
    __syncthreads();
    int c4 = tid & 31;
    int r  = tid >> 5;
    int nvalid = min(256, E - e0);
    for (int j = r; j < nvalid; j += 8) {
        float4 v = {0.f, 0.f, 0.f, 0.f};
#pragma unroll
        for (int a = 0; a < AA; a++) {
            float b = be_sh[j][a];
            v.x += b * anc[a][c4 * 4 + 0];
            v.y += b * anc[a][c4 * 4 + 1];
            v.z += b * anc[a][c4 * 4 + 2];
            v.w += b * anc[a][c4 * 4 + 3];
        }
        *(float4*)(eprompt + (size_t)(e0 + j) * DD + c4 * 4) = v;
    }
}

// ---------------- z = node_x + (gathered coef) @ edge_anchor -> fp16 zh ----------------
__global__ __launch_bounds__(256) void k_z(
    const int* __restrict__ rowptr, const int2* __restrict__ adjpair,
    const float4* __restrict__ be4, const float* __restrict__ be1,
    const float* __restrict__ eanchor, const float* __restrict__ node_x,
    unsigned short* __restrict__ zh, int N)
{
    int tid = threadIdx.x;
    int l32 = tid & 31;
    int u = blockIdx.x * 8 + (tid >> 5);
    if (u >= N) return;
    int beg = rowptr[u], end = rowptr[u + 1];
    float c0 = 0.f, c1 = 0.f, c2 = 0.f, c3 = 0.f, c4v = 0.f;
    for (int j = beg + l32; j < end; j += 32) {
        int e = adjpair[j].y;
        float4 v = be4[e];
        c0 += v.x; c1 += v.y; c2 += v.z; c3 += v.w;
        c4v += be1[e];
    }
#pragma unroll
    for (int off = 16; off >= 1; off >>= 1) {
        c0 += __shfl_xor(c0, off, 64);
        c1 += __shfl_xor(c1, off, 64);
        c2 += __shfl_xor(c2, off, 64);
        c3 += __shfl_xor(c3, off, 64);
        c4v += __shfl_xor(c4v, off, 64);
    }
    float4 v = *(const float4*)(node_x + (size_t)u * DD + l32 * 4);
    const float4 a0 = *(const float4*)(eanchor + 0 * DD + l32 * 4);
    const float4 a1 = *(const float4*)(eanchor + 1 * DD + l32 * 4);
    const float4 a2 = *(const float4*)(eanchor + 2 * DD + l32 * 4);
    const float4 a3 = *(const float4*)(eanchor + 3 * DD + l32 * 4);
    const float4 a4 = *(const float4*)(eanchor + 4 * DD + l32 * 4);
    v.x += c0 * a0.x + c1 * a1.x + c2 * a2.x + c3 * a3.x + c4v * a4.x;
    v.y += c0 * a0.y + c1 * a1.y + c2 * a2.y + c3 * a3.y + c4v * a4.y;
    v.z += c0 * a0.z + c1 * a1.z + c2 * a2.z + c3 * a3.z + c4v * a4.z;
    v.w += c0 * a0.w + c1 * a1.w + c2 * a2.w + c3 * a3.w + c4v * a4.w;
    ushort4 ob;
    ob.x = f2h(v.x); ob.y = f2h(v.y); ob.z = f2h(v.z); ob.w = f2h(v.w);
    *(ushort4*)(zh + (size_t)u * DD + l32 * 4) = ob;
}

// ---------------- CSR build ----------------
__global__ __launch_bounds__(1024) void k_scan(
    const int* __restrict__ deg, int* __restrict__ rowptr, int* __restrict__ wp, int N, int total)
{
    __shared__ int sdata[1024];
    int t = threadIdx.x;
    int chunk = (N + 1023) >> 10;
    int start = t * chunk, end = min(start + chunk, N);
    int lsum = 0;
    for (int i = start; i < end; i++) lsum += deg[i];
    sdata[t] = lsum;
    __syncthreads();
    for (int off = 1; off < 1024; off <<= 1) {
        int v = (t >= off) ? sdata[t - off] : 0;
        __syncthreads();
        sdata[t] += v;
        __syncthreads();
    }
    int run = sdata[t] - lsum;
    for (int i = start; i < end; i++) { rowptr[i] = run; wp[i] = run; run += deg[i]; }
    if (t == 0) rowptr[N] = total;
}

__global__ __launch_bounds__(256) void k_fill(
    const int* __restrict__ ei, int* __restrict__ wp, int2* __restrict__ adjpair, int E)
{
    int e = blockIdx.x * 256 + threadIdx.x;
    if (e >= E) return;
    int s = ei[e], d = ei[E + e];
    int ps = atomicAdd(&wp[s], 1);
    int2 v1; v1.x = d; v1.y = e;
    adjpair[ps] = v1;
    int pd = atomicAdd(&wp[d], 1);
    int2 v2; v2.x = s; v2.y = e;
    adjpair[pd] = v2;
}

// ---------------- wavelet step: fp16 in -> fp16 out (into comb chunk, stride 512) ----------------
template<int IN_STRIDE>
__global__ __launch_bounds__(128) void k_wav(
    const int* __restrict__ rowptr, const int2* __restrict__ adjpair,
    const unsigned short* __restrict__ yin,   // fp16 bits, row stride IN_STRIDE
    unsigned short* __restrict__ yout,        // fp16 bits, row stride 512 (comb chunk base)
    float halfinvnorm, int N)
{
    int nl = threadIdx.x >> 5;
    int c4 = threadIdx.x & 31;
    int u = blockIdx.x * 4 + nl;
    if (u >= N) return;
    int beg = rowptr[u], end = rowptr[u + 1];
    float4 s0 = {0.f, 0.f, 0.f, 0.f}, s1 = {0.f, 0.f, 0.f, 0.f};
    int j = beg;
    for (; j + 1 < end; j += 2) {
        int n0 = adjpair[j].x, n1 = adjpair[j + 1].x;
        const ushort4 v0 = *(const ushort4*)(yin + (size_t)n0 * IN_STRIDE + c4 * 4);
        const ushort4 v1 = *(const ushort4*)(yin + (size_t)n1 * IN_STRIDE + c4 * 4);
        s0.x += h2f(v0.x); s0.y += h2f(v0.y); s0.z += h2f(v0.z); s0.w += h2f(v0.w);
        s1.x += h2f(v1.x); s1.y += h2f(v1.y); s1.z += h2f(v1.z); s1.w += h2f(v1.w);
    }
    if (j < end) {
        int n0 = adjpair[j].x;
        const ushort4 v0 = *(const ushort4*)(yin + (size_t)n0 * IN_STRIDE + c4 * 4);
        s0.x += h2f(v0.x); s0.y += h2f(v0.y); s0.z += h2f(v0.z); s0.w += h2f(v0.w);
    }
    const ushort4 sf = *(const ushort4*)(yin + (size_t)u * IN_STRIDE + c4 * 4);
    float4 o;
    o.x = 0.5f * h2f(sf.x) + halfinvnorm * (s0.x + s1.x);
    o.y = 0.5f * h2f(sf.y) + halfinvnorm * (s0.y + s1.y);
    o.z = 0.5f * h2f(sf.z) + halfinvnorm * (s0.z + s1.z);
    o.w = 0.5f * h2f(sf.w) + halfinvnorm * (s0.w + s1.w);
    ushort4 ob;
    ob.x = f2h(o.x); ob.y = f2h(o.y); ob.z = f2h(o.z); ob.w = f2h(o.w);
    *(ushort4*)(yout + (size_t)u * 512 + c4 * 4) = ob;
}

// ---------------- weight conversion (transposed, fp16) ----------------
__global__ __launch_bounds__(256) void k_cvtw1(
    const float* __restrict__ w1, const float* __restrict__ scales,
    unsigned short* __restrict__ w1t)
{
    int t = blockIdx.x * 256 + threadIdx.x;
    if (t >= 512 * 256) return;
    int k = t >> 8, n = t & 255;
    w1t[n * 512 + k] = f2h(w1[t] * scales[k >> 7]);
}

__global__ __launch_bounds__(256) void k_cvtw2(
    const float* __restrict__ w2, unsigned short* __restrict__ w2t)
{
    int t = blockIdx.x * 256 + threadIdx.x;
    if (t >= 256 * 128) return;
    int k = t >> 7, n = t & 127;
    w2t[n * 256 + k] = f2h(w2[t]);
}

// ---------------- MFMA GEMM (fp16): out[N,NOUT] = A[N,K] @ Bt[NOUT,K]^T + bias ----------------
template<int K, bool RELU_F16>
__global__ __launch_bounds__(256) void k_gemm(
    const unsigned short* __restrict__ A, const unsigned short* __restrict__ Bt,
    const float* __restrict__ bias, void* __restrict__ outp, int N, int NOUT)
{
    __shared__ short sA[128][40];
    __shared__ short sB[64][40];
    int tid = threadIdx.x;
    int r0 = blockIdx.x * 128;
    int n0 = blockIdx.y * 64;
    int lane = tid & 63;
    int w = tid >> 6;
    int quad = lane >> 4;
    int lrow = lane & 15;

    f32x4 acc[2][4];
#pragma unroll
    for (int s = 0; s < 2; s++)
#pragma unroll
        for (int t = 0; t < 4; t++) acc[s][t] = (f32x4){0.f, 0.f, 0.f, 0.f};

    for (int k0 = 0; k0 < K; k0 += 32) {
#pragma unroll
        for (int i = 0; i < 2; i++) {
            int c = tid + i * 256;
            int row = c >> 2, col = (c & 3) * 8;
            ushort4 v2[2];
            if (r0 + row < N) {
                const uint4 g = *(const uint4*)(A + (size_t)(r0 + row) * K + k0 + col);
                *(uint4*)v2 = g;
            } else {
                v2[0] = (ushort4){0,0,0,0}; v2[1] = (ushort4){0,0,0,0};
            }
            *(uint4*)&sA[row][col] = *(uint4*)v2;
        }
        {
            int row = tid >> 2, col = (tid & 3) * 8;
            const uint4 g = *(const uint4*)(Bt + (size_t)(n0 + row) * K + k0 + col);
            *(uint4*)&sB[row][col] = g;
        }
        __syncthreads();
        half8 afr[2], bfr[4];
#pragma unroll
        for (int s = 0; s < 2; s++)
            afr[s] = *(const half8*)&sA[w * 32 + s * 16 + lrow][quad * 8];
#pragma unroll
        for (int t = 0; t < 4; t++)
            bfr[t] = *(const half8*)&sB[t * 16 + lrow][quad * 8];
#pragma unroll
        for (int s = 0; s < 2; s++)
#pragma unroll
            for (int t = 0; t < 4; t++)
                acc[s][t] = __builtin_amdgcn_mfma_f32_16x16x32_f16(afr[s], bfr[t], acc[s][t], 0, 0, 0);
        __syncthreads();
    }
#pragma unroll
    for (int s = 0; s < 2; s++) {
#pragma unroll
        for (int t = 0; t < 4; t++) {
            int col = n0 + t * 16 + lrow;
            float bb = bias[col];
#pragma unroll
            for (int r = 0; r < 4; r++) {
                int row = r0 + w * 32 + s * 16 + quad * 4 + r;
                if (row < N) {
                    float v = acc[s][t][r] + bb;
                    if (RELU_F16) {
                        ((unsigned short*)outp)[(size_t)row * NOUT + col] = f2h(fmaxf(v, 0.f));
                    } else {
                        ((float*)outp)[(size_t)row * NOUT + col] = v;
                    }
                }
            }
        }
    }
}

extern "C" void kernel_launch(void* const* d_in, const int* in_sizes, int n_in,
                              void* d_out, int out_size, void* d_ws, size_t ws_size,
                              hipStream_t stream)
{
    const float* x       = (const float*)d_in[0];
    const int*   ei      = (const int*)d_in[1];
    const float* nanchor = (const float*)d_in[2];
    const float* naw     = (const float*)d_in[3];
    const float* nab     = (const float*)d_in[4];
    const float* eanchor = (const float*)d_in[5];
    const float* eww     = (const float*)d_in[6];
    const float* ewb     = (const float*)d_in[7];
    const float* scales  = (const float*)d_in[8];
    const float* w1      = (const float*)d_in[9];
    const float* b1      = (const float*)d_in[10];
    const float* w2      = (const float*)d_in[11];
    const float* b2      = (const float*)d_in[12];

    int N = in_sizes[0] / DD;
    int E = in_sizes[1] / 2;
    float norm = (float)((double)E / (double)N + 1e-6);
    float hin = 0.5f / norm;

    char* wsb = (char*)d_ws;
    size_t off = 0;
    auto alloc = [&](size_t b) -> char* {
        char* p = wsb + off;
        off += (b + 255) & ~(size_t)255;
        return p;
    };
    float* node_x = (float*)alloc((size_t)N * DD * 4);
    float* p1     = (float*)alloc((size_t)N * 8 * 4);
    float* p2     = (float*)alloc((size_t)N * 8 * 4);
    unsigned short* zh      = (unsigned short*)alloc((size_t)N * DD * 2);
    unsigned short* comb_h  = (unsigned short*)alloc((size_t)N * 512 * 2);
    unsigned short* h_h     = (unsigned short*)alloc((size_t)N * 256 * 2);
    unsigned short* w1t     = (unsigned short*)alloc((size_t)512 * 256 * 2);
    unsigned short* w2t     = (unsigned short*)alloc((size_t)256 * 128 * 2);
    int*   deg    = (int*)alloc((size_t)N * 4);
    int*   rowptr = (int*)alloc((size_t)(N + 1) * 4);
    int*   wp     = (int*)alloc((size_t)N * 4);
    int2*  adjpair= (int2*)alloc((size_t)2 * E * 8);
    float4* be4   = (float4*)alloc((size_t)E * 16);
    float*  be1   = (float*)alloc((size_t)E * 4);

    float* out_final   = (float*)d_out;
    float* out_eprompt = out_final + (size_t)N * DD;

    hipMemsetAsync(deg, 0, (size_t)N * 4, stream);

    k_cvtw1<<<(512 * 256 + 255) / 256, 256, 0, stream>>>(w1, scales, w1t);
    k_cvtw2<<<(256 * 128 + 255) / 256, 256, 0, stream>>>(w2, w2t);

    k_node_pre<<<(N + 3) / 4, 256, 0, stream>>>(x, naw, nab, nanchor, eww, node_x, p1, p2, N);
    k_edge<<<(E + 255) / 256, 256, 0, stream>>>(ei, p1, p2, ewb, eanchor, out_eprompt, be4, be1, deg, E);
    k_scan<<<1, 1024, 0, stream>>>(deg, rowptr, wp, N, 2 * E);
    k_fill<<<(E + 255) / 256, 256, 0, stream>>>(ei, wp, adjpair, E);
    k_z<<<(N + 7) / 8, 256, 0, stream>>>(rowptr, adjpair, be4, be1, eanchor, node_x, zh, N);

    // 4 chained wavelet steps, fully fp16: zh -> comb chunk0 -> chunk1 -> chunk2 -> chunk3
    k_wav<DD><<<(N + 3) / 4, 128, 0, stream>>>(rowptr, adjpair, zh, comb_h + 0, hin, N);
    k_wav<512><<<(N + 3) / 4, 128, 0, stream>>>(rowptr, adjpair, comb_h + 0,   comb_h + 128, hin, N);
    k_wav<512><<<(N + 3) / 4, 128, 0, stream>>>(rowptr, adjpair, comb_h + 128, comb_h + 256, hin, N);
    k_wav<512><<<(N + 3) / 4, 128, 0, stream>>>(rowptr, adjpair, comb_h + 256, comb_h + 384, hin, N);

    dim3 g1((N + 127) / 128, 4);
    k_gemm<512, true><<<g1, 256, 0, stream>>>(comb_h, w1t, b1, h_h, N, 256);
    dim3 g2((N + 127) / 128, 2);
    k_gemm<256, false><<<g2, 256, 0, stream>>>(h_h, w2t, b2, out_final, N, 128);
}

// Round 6
// 1019.309 us; speedup vs baseline: 1.3901x; 1.0658x over previous
//
#include <hip/hip_runtime.h>
#include <hip/hip_bf16.h>

#define DD 128
#define AA 5

typedef short short8 __attribute__((ext_vector_type(8)));
typedef _Float16 half8 __attribute__((ext_vector_type(8)));
typedef float f32x4 __attribute__((ext_vector_type(4)));

static __device__ __forceinline__ unsigned short f2h(float f) {
    union { _Float16 h; unsigned short u; } v;
    v.h = (_Float16)f;
    return v.u;
}
static __device__ __forceinline__ float h2f(unsigned short u) {
    union { unsigned short u; _Float16 h; } v;
    v.u = u;
    return (float)v.h;
}

// ---------------- node precompute: node_x, p1, p2 (+ deg clear) ----------------
__global__ __launch_bounds__(256) void k_node_pre(
    const float* __restrict__ x, const float* __restrict__ naw, const float* __restrict__ nab,
    const float* __restrict__ nanchor, const float* __restrict__ eww,
    float* __restrict__ node_x, float* __restrict__ p1, float* __restrict__ p2,
    int* __restrict__ deg, int N)
{
    // fused deg clear (replaces hipMemsetAsync)
    int cu = blockIdx.x * 4 + threadIdx.x;
    if (threadIdx.x < 4 && cu < N) deg[cu] = 0;

    int wave = threadIdx.x >> 6;
    int lane = threadIdx.x & 63;
    int u = blockIdx.x * 4 + wave;
    if (u >= N) return;
    int d0 = lane * 2;
    float2 xv = *(const float2*)(x + (size_t)u * DD + d0);
    float nl[AA], a1[AA], a2[AA];
#pragma unroll
    for (int a = 0; a < AA; a++) {
        nl[a] = xv.x * naw[d0 * AA + a] + xv.y * naw[(d0 + 1) * AA + a];
        a1[a] = xv.x * eww[d0 * AA + a] + xv.y * eww[(d0 + 1) * AA + a];
        a2[a] = xv.x * eww[(DD + d0) * AA + a] + xv.y * eww[(DD + d0 + 1) * AA + a];
    }
#pragma unroll
    for (int off = 32; off >= 1; off >>= 1) {
#pragma unroll
        for (int a = 0; a < AA; a++) {
            nl[a] += __shfl_xor(nl[a], off, 64);
            a1[a] += __shfl_xor(a1[a], off, 64);
            a2[a] += __shfl_xor(a2[a], off, 64);
        }
    }
    float m = -1e30f;
#pragma unroll
    for (int a = 0; a < AA; a++) { nl[a] += nab[a]; m = fmaxf(m, nl[a]); }
    float ssum = 0.f;
#pragma unroll
    for (int a = 0; a < AA; a++) { nl[a] = __expf(nl[a] - m); ssum += nl[a]; }
    float inv = 1.0f / ssum;
    float2 o = xv;
#pragma unroll
    for (int a = 0; a < AA; a++) {
        float wgt = nl[a] * inv;
        o.x += wgt * nanchor[a * DD + d0];
        o.y += wgt * nanchor[a * DD + d0 + 1];
    }
    *(float2*)(node_x + (size_t)u * DD + d0) = o;
    if (lane == 0) {
#pragma unroll
        for (int a = 0; a < AA; a++) { p1[u * 8 + a] = a1[a]; p2[u * 8 + a] = a2[a]; }
    }
}

// ---------------- edge kernel: softmax coeffs -> dense store + deg atomics ----------------
__global__ __launch_bounds__(256) void k_edge(
    const int* __restrict__ ei, const float* __restrict__ p1, const float* __restrict__ p2,
    const float* __restrict__ ewb, const float* __restrict__ eanchor,
    float* __restrict__ eprompt, float4* __restrict__ be4, float* __restrict__ be1,
    int* __restrict__ deg, int E)
{
    __shared__ float be_sh[256][6];
    __shared__ float anc[AA][DD];
    int tid = threadIdx.x;
    for (int i = tid; i < AA * DD; i += 256) anc[i / DD][i % DD] = eanchor[i];
    int e0 = blockIdx.x * 256;
    int e = e0 + tid;
    if (e < E) {
        int s = ei[e], d = ei[E + e];
        atomicAdd(&deg[s], 1);
        atomicAdd(&deg[d], 1);
        float l[AA];
        float4 q1 = *(const float4*)(p1 + (size_t)s * 8);
        float  q1e = p1[(size_t)s * 8 + 4];
        float4 q2 = *(const float4*)(p2 + (size_t)d * 8);
        float  q2e = p2[(size_t)d * 8 + 4];
        l[0] = q1.x + q2.x; l[1] = q1.y + q2.y; l[2] = q1.z + q2.z; l[3] = q1.w + q2.w; l[4] = q1e + q2e;
        float m = -1e30f;
#pragma unroll
        for (int a = 0; a < AA; a++) {
            l[a] += ewb[a];
            l[a] = l[a] >= 0.f ? l[a] : 0.01f * l[a];
            m = fmaxf(m, l[a]);
        }
        float ssum = 0.f;
#pragma unroll
        for (int a = 0; a < AA; a++) { l[a] = __expf(l[a] - m); ssum += l[a]; }
        float inv = 1.f / ssum;
#pragma unroll
        for (int a = 0; a < AA; a++) {
            float b = l[a] * inv;
            be_sh[tid][a] = b;
        }
        float4 w;
        w.x = be_sh[tid][0]; w.y = be_sh[tid][1]; w.z = be_sh[tid][2]; w.w = be_sh[tid][3];
        be4[e] = w;
        be1[e] = be_sh[tid][4];
    }
    __syncthreads();
    int c4 = tid & 31;
    int r  = tid >> 5;
    int nvalid = min(256, E - e0);
    for (int j = r; j < nvalid; j += 8) {
        f32x4 v = {0.f, 0.f, 0.f, 0.f};
#pragma unroll
        for (int a = 0; a < AA; a++) {
            float b = be_sh[j][a];
            v.x += b * anc[a][c4 * 4 + 0];
            v.y += b * anc[a][c4 * 4 + 1];
            v.z += b * anc[a][c4 * 4 + 2];
            v.w += b * anc[a][c4 * 4 + 3];
        }
        // streaming output, never re-read: keep it out of L2/L3
        // (ext_vector type f32x4 — __builtin_nontemporal_store rejects HIP_vector_type float4)
        __builtin_nontemporal_store(v, (f32x4*)(eprompt + (size_t)(e0 + j) * DD + c4 * 4));
    }
}

// ---------------- z = node_x + (gathered coef) @ edge_anchor -> fp16 zh ----------------
__global__ __launch_bounds__(256) void k_z(
    const int* __restrict__ rowptr, const int2* __restrict__ adjpair,
    const float4* __restrict__ be4, const float* __restrict__ be1,
    const float* __restrict__ eanchor, const float* __restrict__ node_x,
    unsigned short* __restrict__ zh, int N)
{
    int tid = threadIdx.x;
    int l32 = tid & 31;
    int u = blockIdx.x * 8 + (tid >> 5);
    if (u >= N) return;
    int beg = rowptr[u], end = rowptr[u + 1];
    float c0 = 0.f, c1 = 0.f, c2 = 0.f, c3 = 0.f, c4v = 0.f;
    for (int j = beg + l32; j < end; j += 32) {
        int e = adjpair[j].y;
        float4 v = be4[e];
        c0 += v.x; c1 += v.y; c2 += v.z; c3 += v.w;
        c4v += be1[e];
    }
#pragma unroll
    for (int off = 16; off >= 1; off >>= 1) {
        c0 += __shfl_xor(c0, off, 64);
        c1 += __shfl_xor(c1, off, 64);
        c2 += __shfl_xor(c2, off, 64);
        c3 += __shfl_xor(c3, off, 64);
        c4v += __shfl_xor(c4v, off, 64);
    }
    float4 v = *(const float4*)(node_x + (size_t)u * DD + l32 * 4);
    const float4 a0 = *(const float4*)(eanchor + 0 * DD + l32 * 4);
    const float4 a1 = *(const float4*)(eanchor + 1 * DD + l32 * 4);
    const float4 a2 = *(const float4*)(eanchor + 2 * DD + l32 * 4);
    const float4 a3 = *(const float4*)(eanchor + 3 * DD + l32 * 4);
    const float4 a4 = *(const float4*)(eanchor + 4 * DD + l32 * 4);
    v.x += c0 * a0.x + c1 * a1.x + c2 * a2.x + c3 * a3.x + c4v * a4.x;
    v.y += c0 * a0.y + c1 * a1.y + c2 * a2.y + c3 * a3.y + c4v * a4.y;
    v.z += c0 * a0.z + c1 * a1.z + c2 * a2.z + c3 * a3.z + c4v * a4.z;
    v.w += c0 * a0.w + c1 * a1.w + c2 * a2.w + c3 * a3.w + c4v * a4.w;
    ushort4 ob;
    ob.x = f2h(v.x); ob.y = f2h(v.y); ob.z = f2h(v.z); ob.w = f2h(v.w);
    *(ushort4*)(zh + (size_t)u * DD + l32 * 4) = ob;
}

// ---------------- CSR build ----------------
__global__ __launch_bounds__(1024) void k_scan(
    const int* __restrict__ deg, int* __restrict__ rowptr, int* __restrict__ wp, int N, int total)
{
    __shared__ int sdata[1024];
    int t = threadIdx.x;
    int chunk = (N + 1023) >> 10;
    int start = t * chunk, end = min(start + chunk, N);
    int lsum = 0;
    for (int i = start; i < end; i++) lsum += deg[i];
    sdata[t] = lsum;
    __syncthreads();
    for (int off = 1; off < 1024; off <<= 1) {
        int v = (t >= off) ? sdata[t - off] : 0;
        __syncthreads();
        sdata[t] += v;
        __syncthreads();
    }
    int run = sdata[t] - lsum;
    for (int i = start; i < end; i++) { rowptr[i] = run; wp[i] = run; run += deg[i]; }
    if (t == 0) rowptr[N] = total;
}

__global__ __launch_bounds__(256) void k_fill(
    const int* __restrict__ ei, int* __restrict__ wp, int2* __restrict__ adjpair, int E)
{
    int e = blockIdx.x * 256 + threadIdx.x;
    if (e >= E) return;
    int s = ei[e], d = ei[E + e];
    int ps = atomicAdd(&wp[s], 1);
    int2 v1; v1.x = d; v1.y = e;
    adjpair[ps] = v1;
    int pd = atomicAdd(&wp[d], 1);
    int2 v2; v2.x = s; v2.y = e;
    adjpair[pd] = v2;
}

// ---------------- wavelet step: fp16 in -> fp16 out (into comb chunk, stride 512) ----
// R2-proven pattern: 32 lanes per row, ushort4 (8B)/lane, 2-neighbor unroll.
// 256-thread blocks = 8 nodes/block.
template<int IN_STRIDE>
__global__ __launch_bounds__(256) void k_wav(
    const int* __restrict__ rowptr, const int2* __restrict__ adjpair,
    const unsigned short* __restrict__ yin,
    unsigned short* __restrict__ yout,
    float halfinvnorm, int N)
{
    int g  = threadIdx.x >> 5;
    int c4 = threadIdx.x & 31;
    int u = blockIdx.x * 8 + g;
    if (u >= N) return;
    int beg = rowptr[u], end = rowptr[u + 1];
    float4 s0 = {0.f, 0.f, 0.f, 0.f}, s1 = {0.f, 0.f, 0.f, 0.f};
    int j = beg;
    for (; j + 1 < end; j += 2) {
        int n0 = adjpair[j].x, n1 = adjpair[j + 1].x;
        const ushort4 v0 = *(const ushort4*)(yin + (size_t)n0 * IN_STRIDE + c4 * 4);
        const ushort4 v1 = *(const ushort4*)(yin + (size_t)n1 * IN_STRIDE + c4 * 4);
        s0.x += h2f(v0.x); s0.y += h2f(v0.y); s0.z += h2f(v0.z); s0.w += h2f(v0.w);
        s1.x += h2f(v1.x); s1.y += h2f(v1.y); s1.z += h2f(v1.z); s1.w += h2f(v1.w);
    }
    if (j < end) {
        int n0 = adjpair[j].x;
        const ushort4 v0 = *(const ushort4*)(yin + (size_t)n0 * IN_STRIDE + c4 * 4);
        s0.x += h2f(v0.x); s0.y += h2f(v0.y); s0.z += h2f(v0.z); s0.w += h2f(v0.w);
    }
    const ushort4 sf = *(const ushort4*)(yin + (size_t)u * IN_STRIDE + c4 * 4);
    float4 o;
    o.x = 0.5f * h2f(sf.x) + halfinvnorm * (s0.x + s1.x);
    o.y = 0.5f * h2f(sf.y) + halfinvnorm * (s0.y + s1.y);
    o.z = 0.5f * h2f(sf.z) + halfinvnorm * (s0.z + s1.z);
    o.w = 0.5f * h2f(sf.w) + halfinvnorm * (s0.w + s1.w);
    ushort4 ob;
    ob.x = f2h(o.x); ob.y = f2h(o.y); ob.z = f2h(o.z); ob.w = f2h(o.w);
    *(ushort4*)(yout + (size_t)u * 512 + c4 * 4) = ob;
}

// ---------------- weight conversion (transposed, fp16) — merged ----------------
__global__ __launch_bounds__(256) void k_cvtw(
    const float* __restrict__ w1, const float* __restrict__ scales,
    const float* __restrict__ w2,
    unsigned short* __restrict__ w1t, unsigned short* __restrict__ w2t)
{
    int t = blockIdx.x * 256 + threadIdx.x;
    if (t < 512 * 256) {
        int k = t >> 8, n = t & 255;
        w1t[n * 512 + k] = f2h(w1[t] * scales[k >> 7]);
    } else {
        int t2 = t - 512 * 256;
        if (t2 < 256 * 128) {
            int k = t2 >> 7, n = t2 & 127;
            w2t[n * 256 + k] = f2h(w2[t2]);
        }
    }
}

// ---------------- MFMA GEMM (fp16): out[N,NOUT] = A[N,K] @ Bt[NOUT,K]^T + bias ----------------
template<int K, bool RELU_F16>
__global__ __launch_bounds__(256) void k_gemm(
    const unsigned short* __restrict__ A, const unsigned short* __restrict__ Bt,
    const float* __restrict__ bias, void* __restrict__ outp, int N, int NOUT)
{
    __shared__ short sA[128][40];
    __shared__ short sB[64][40];
    int tid = threadIdx.x;
    int r0 = blockIdx.x * 128;
    int n0 = blockIdx.y * 64;
    int lane = tid & 63;
    int w = tid >> 6;
    int quad = lane >> 4;
    int lrow = lane & 15;

    f32x4 acc[2][4];
#pragma unroll
    for (int s = 0; s < 2; s++)
#pragma unroll
        for (int t = 0; t < 4; t++) acc[s][t] = (f32x4){0.f, 0.f, 0.f, 0.f};

    for (int k0 = 0; k0 < K; k0 += 32) {
#pragma unroll
        for (int i = 0; i < 2; i++) {
            int c = tid + i * 256;
            int row = c >> 2, col = (c & 3) * 8;
            ushort4 v2[2];
            if (r0 + row < N) {
                const uint4 g = *(const uint4*)(A + (size_t)(r0 + row) * K + k0 + col);
                *(uint4*)v2 = g;
            } else {
                v2[0] = (ushort4){0,0,0,0}; v2[1] = (ushort4){0,0,0,0};
            }
            *(uint4*)&sA[row][col] = *(uint4*)v2;
        }
        {
            int row = tid >> 2, col = (tid & 3) * 8;
            const uint4 g = *(const uint4*)(Bt + (size_t)(n0 + row) * K + k0 + col);
            *(uint4*)&sB[row][col] = g;
        }
        __syncthreads();
        half8 afr[2], bfr[4];
#pragma unroll
        for (int s = 0; s < 2; s++)
            afr[s] = *(const half8*)&sA[w * 32 + s * 16 + lrow][quad * 8];
#pragma unroll
        for (int t = 0; t < 4; t++)
            bfr[t] = *(const half8*)&sB[t * 16 + lrow][quad * 8];
#pragma unroll
        for (int s = 0; s < 2; s++)
#pragma unroll
            for (int t = 0; t < 4; t++)
                acc[s][t] = __builtin_amdgcn_mfma_f32_16x16x32_f16(afr[s], bfr[t], acc[s][t], 0, 0, 0);
        __syncthreads();
    }
#pragma unroll
    for (int s = 0; s < 2; s++) {
#pragma unroll
        for (int t = 0; t < 4; t++) {
            int col = n0 + t * 16 + lrow;
            float bb = bias[col];
#pragma unroll
            for (int r = 0; r < 4; r++) {
                int row = r0 + w * 32 + s * 16 + quad * 4 + r;
                if (row < N) {
                    float v = acc[s][t][r] + bb;
                    if (RELU_F16) {
                        ((unsigned short*)outp)[(size_t)row * NOUT + col] = f2h(fmaxf(v, 0.f));
                    } else {
                        // final output: streaming, never re-read (scalar float — legal for the builtin)
                        __builtin_nontemporal_store(v, (float*)outp + (size_t)row * NOUT + col);
                    }
                }
            }
        }
    }
}

extern "C" void kernel_launch(void* const* d_in, const int* in_sizes, int n_in,
                              void* d_out, int out_size, void* d_ws, size_t ws_size,
                              hipStream_t stream)
{
    const float* x       = (const float*)d_in[0];
    const int*   ei      = (const int*)d_in[1];
    const float* nanchor = (const float*)d_in[2];
    const float* naw     = (const float*)d_in[3];
    const float* nab     = (const float*)d_in[4];
    const float* eanchor = (const float*)d_in[5];
    const float* eww     = (const float*)d_in[6];
    const float* ewb     = (const float*)d_in[7];
    const float* scales  = (const float*)d_in[8];
    const float* w1      = (const float*)d_in[9];
    const float* b1      = (const float*)d_in[10];
    const float* w2      = (const float*)d_in[11];
    const float* b2      = (const float*)d_in[12];

    int N = in_sizes[0] / DD;
    int E = in_sizes[1] / 2;
    float norm = (float)((double)E / (double)N + 1e-6);
    float hin = 0.5f / norm;

    char* wsb = (char*)d_ws;
    size_t off = 0;
    auto alloc = [&](size_t b) -> char* {
        char* p = wsb + off;
        off += (b + 255) & ~(size_t)255;
        return p;
    };
    float* node_x = (float*)alloc((size_t)N * DD * 4);
    float* p1     = (float*)alloc((size_t)N * 8 * 4);
    float* p2     = (float*)alloc((size_t)N * 8 * 4);
    unsigned short* zh      = (unsigned short*)alloc((size_t)N * DD * 2);
    unsigned short* comb_h  = (unsigned short*)alloc((size_t)N * 512 * 2);
    unsigned short* h_h     = (unsigned short*)alloc((size_t)N * 256 * 2);
    unsigned short* w1t     = (unsigned short*)alloc((size_t)512 * 256 * 2);
    unsigned short* w2t     = (unsigned short*)alloc((size_t)256 * 128 * 2);
    int*   deg    = (int*)alloc((size_t)N * 4);
    int*   rowptr = (int*)alloc((size_t)(N + 1) * 4);
    int*   wp     = (int*)alloc((size_t)N * 4);
    int2*  adjpair= (int2*)alloc((size_t)2 * E * 8);
    float4* be4   = (float4*)alloc((size_t)E * 16);
    float*  be1   = (float*)alloc((size_t)E * 4);

    float* out_final   = (float*)d_out;
    float* out_eprompt = out_final + (size_t)N * DD;

    k_cvtw<<<(512 * 256 + 256 * 128 + 255) / 256, 256, 0, stream>>>(w1, scales, w2, w1t, w2t);

    k_node_pre<<<(N + 3) / 4, 256, 0, stream>>>(x, naw, nab, nanchor, eww, node_x, p1, p2, deg, N);
    k_edge<<<(E + 255) / 256, 256, 0, stream>>>(ei, p1, p2, ewb, eanchor, out_eprompt, be4, be1, deg, E);
    k_scan<<<1, 1024, 0, stream>>>(deg, rowptr, wp, N, 2 * E);
    k_fill<<<(E + 255) / 256, 256, 0, stream>>>(ei, wp, adjpair, E);
    k_z<<<(N + 7) / 8, 256, 0, stream>>>(rowptr, adjpair, be4, be1, eanchor, node_x, zh, N);

    // 4 chained wavelet steps, fully fp16: zh -> comb chunk0 -> chunk1 -> chunk2 -> chunk3
    k_wav<DD><<<(N + 7) / 8, 256, 0, stream>>>(rowptr, adjpair, zh, comb_h + 0, hin, N);
    k_wav<512><<<(N + 7) / 8, 256, 0, stream>>>(rowptr, adjpair, comb_h + 0,   comb_h + 128, hin, N);
    k_wav<512><<<(N + 7) / 8, 256, 0, stream>>>(rowptr, adjpair, comb_h + 128, comb_h + 256, hin, N);
    k_wav<512><<<(N + 7) / 8, 256, 0, stream>>>(rowptr, adjpair, comb_h + 256, comb_h + 384, hin, N);

    dim3 g1((N + 127) / 128, 4);
    k_gemm<512, true><<<g1, 256, 0, stream>>>(comb_h, w1t, b1, h_h, N, 256);
    dim3 g2((N + 127) / 128, 2);
    k_gemm<256, false><<<g2, 256, 0, stream>>>(h_h, w2t, b2, out_final, N, 128);
}

// Round 7
// 966.704 us; speedup vs baseline: 1.4657x; 1.0544x over previous
//
#include <hip/hip_runtime.h>
#include <hip/hip_bf16.h>

#define DD 128
#define AA 5

typedef short short8 __attribute__((ext_vector_type(8)));
typedef _Float16 half8 __attribute__((ext_vector_type(8)));
typedef float f32x4 __attribute__((ext_vector_type(4)));

static __device__ __forceinline__ unsigned short f2h(float f) {
    union { _Float16 h; unsigned short u; } v;
    v.h = (_Float16)f;
    return v.u;
}
static __device__ __forceinline__ float h2f(unsigned short u) {
    union { unsigned short u; _Float16 h; } v;
    v.u = u;
    return (float)v.h;
}

// ---------------- node precompute: node_x, p1, p2 (+ deg clear) ----------------
__global__ __launch_bounds__(256) void k_node_pre(
    const float* __restrict__ x, const float* __restrict__ naw, const float* __restrict__ nab,
    const float* __restrict__ nanchor, const float* __restrict__ eww,
    float* __restrict__ node_x, float* __restrict__ p1, float* __restrict__ p2,
    int* __restrict__ deg, int N)
{
    // fused deg clear (replaces hipMemsetAsync)
    int cu = blockIdx.x * 4 + threadIdx.x;
    if (threadIdx.x < 4 && cu < N) deg[cu] = 0;

    int wave = threadIdx.x >> 6;
    int lane = threadIdx.x & 63;
    int u = blockIdx.x * 4 + wave;
    if (u >= N) return;
    int d0 = lane * 2;
    float2 xv = *(const float2*)(x + (size_t)u * DD + d0);
    float nl[AA], a1[AA], a2[AA];
#pragma unroll
    for (int a = 0; a < AA; a++) {
        nl[a] = xv.x * naw[d0 * AA + a] + xv.y * naw[(d0 + 1) * AA + a];
        a1[a] = xv.x * eww[d0 * AA + a] + xv.y * eww[(d0 + 1) * AA + a];
        a2[a] = xv.x * eww[(DD + d0) * AA + a] + xv.y * eww[(DD + d0 + 1) * AA + a];
    }
#pragma unroll
    for (int off = 32; off >= 1; off >>= 1) {
#pragma unroll
        for (int a = 0; a < AA; a++) {
            nl[a] += __shfl_xor(nl[a], off, 64);
            a1[a] += __shfl_xor(a1[a], off, 64);
            a2[a] += __shfl_xor(a2[a], off, 64);
        }
    }
    float m = -1e30f;
#pragma unroll
    for (int a = 0; a < AA; a++) { nl[a] += nab[a]; m = fmaxf(m, nl[a]); }
    float ssum = 0.f;
#pragma unroll
    for (int a = 0; a < AA; a++) { nl[a] = __expf(nl[a] - m); ssum += nl[a]; }
    float inv = 1.0f / ssum;
    float2 o = xv;
#pragma unroll
    for (int a = 0; a < AA; a++) {
        float wgt = nl[a] * inv;
        o.x += wgt * nanchor[a * DD + d0];
        o.y += wgt * nanchor[a * DD + d0 + 1];
    }
    *(float2*)(node_x + (size_t)u * DD + d0) = o;
    if (lane == 0) {
#pragma unroll
        for (int a = 0; a < AA; a++) { p1[u * 8 + a] = a1[a]; p2[u * 8 + a] = a2[a]; }
    }
}

// ---------------- edge kernel: softmax coeffs -> packed 32B record + deg atomics ------
__global__ __launch_bounds__(256) void k_edge(
    const int* __restrict__ ei, const float* __restrict__ p1, const float* __restrict__ p2,
    const float* __restrict__ ewb, const float* __restrict__ eanchor,
    float* __restrict__ eprompt, float* __restrict__ bes,
    int* __restrict__ deg, int E)
{
    __shared__ float be_sh[256][6];
    __shared__ float anc[AA][DD];
    int tid = threadIdx.x;
    for (int i = tid; i < AA * DD; i += 256) anc[i / DD][i % DD] = eanchor[i];
    int e0 = blockIdx.x * 256;
    int e = e0 + tid;
    if (e < E) {
        int s = ei[e], d = ei[E + e];
        atomicAdd(&deg[s], 1);
        atomicAdd(&deg[d], 1);
        float l[AA];
        float4 q1 = *(const float4*)(p1 + (size_t)s * 8);
        float  q1e = p1[(size_t)s * 8 + 4];
        float4 q2 = *(const float4*)(p2 + (size_t)d * 8);
        float  q2e = p2[(size_t)d * 8 + 4];
        l[0] = q1.x + q2.x; l[1] = q1.y + q2.y; l[2] = q1.z + q2.z; l[3] = q1.w + q2.w; l[4] = q1e + q2e;
        float m = -1e30f;
#pragma unroll
        for (int a = 0; a < AA; a++) {
            l[a] += ewb[a];
            l[a] = l[a] >= 0.f ? l[a] : 0.01f * l[a];
            m = fmaxf(m, l[a]);
        }
        float ssum = 0.f;
#pragma unroll
        for (int a = 0; a < AA; a++) { l[a] = __expf(l[a] - m); ssum += l[a]; }
        float inv = 1.f / ssum;
#pragma unroll
        for (int a = 0; a < AA; a++) {
            float b = l[a] * inv;
            be_sh[tid][a] = b;
        }
        // packed 32B record: coefficients for this edge live in ONE cache line
        float4 w;
        w.x = be_sh[tid][0]; w.y = be_sh[tid][1]; w.z = be_sh[tid][2]; w.w = be_sh[tid][3];
        *(float4*)(bes + (size_t)e * 8) = w;
        bes[(size_t)e * 8 + 4] = be_sh[tid][4];
    }
    __syncthreads();
    int c4 = tid & 31;
    int r  = tid >> 5;
    int nvalid = min(256, E - e0);
    for (int j = r; j < nvalid; j += 8) {
        f32x4 v = {0.f, 0.f, 0.f, 0.f};
#pragma unroll
        for (int a = 0; a < AA; a++) {
            float b = be_sh[j][a];
            v.x += b * anc[a][c4 * 4 + 0];
            v.y += b * anc[a][c4 * 4 + 1];
            v.z += b * anc[a][c4 * 4 + 2];
            v.w += b * anc[a][c4 * 4 + 3];
        }
        // streaming output, never re-read: keep it out of L2/L3
        __builtin_nontemporal_store(v, (f32x4*)(eprompt + (size_t)(e0 + j) * DD + c4 * 4));
    }
}

// ---------------- z = node_x + (gathered coef) @ edge_anchor -> fp16 zh ----------------
__global__ __launch_bounds__(256) void k_z(
    const int* __restrict__ rowptr, const int2* __restrict__ adjpair,
    const float* __restrict__ bes,
    const float* __restrict__ eanchor, const float* __restrict__ node_x,
    unsigned short* __restrict__ zh, int N)
{
    int tid = threadIdx.x;
    int l32 = tid & 31;
    int u = blockIdx.x * 8 + (tid >> 5);
    if (u >= N) return;
    int beg = rowptr[u], end = rowptr[u + 1];
    float c0 = 0.f, c1 = 0.f, c2 = 0.f, c3 = 0.f, c4v = 0.f;
    for (int j = beg + l32; j < end; j += 32) {
        int e = adjpair[j].y;
        float4 v = *(const float4*)(bes + (size_t)e * 8);
        c0 += v.x; c1 += v.y; c2 += v.z; c3 += v.w;
        c4v += bes[(size_t)e * 8 + 4];
    }
#pragma unroll
    for (int off = 16; off >= 1; off >>= 1) {
        c0 += __shfl_xor(c0, off, 64);
        c1 += __shfl_xor(c1, off, 64);
        c2 += __shfl_xor(c2, off, 64);
        c3 += __shfl_xor(c3, off, 64);
        c4v += __shfl_xor(c4v, off, 64);
    }
    float4 v = *(const float4*)(node_x + (size_t)u * DD + l32 * 4);
    const float4 a0 = *(const float4*)(eanchor + 0 * DD + l32 * 4);
    const float4 a1 = *(const float4*)(eanchor + 1 * DD + l32 * 4);
    const float4 a2 = *(const float4*)(eanchor + 2 * DD + l32 * 4);
    const float4 a3 = *(const float4*)(eanchor + 3 * DD + l32 * 4);
    const float4 a4 = *(const float4*)(eanchor + 4 * DD + l32 * 4);
    v.x += c0 * a0.x + c1 * a1.x + c2 * a2.x + c3 * a3.x + c4v * a4.x;
    v.y += c0 * a0.y + c1 * a1.y + c2 * a2.y + c3 * a3.y + c4v * a4.y;
    v.z += c0 * a0.z + c1 * a1.z + c2 * a2.z + c3 * a3.z + c4v * a4.z;
    v.w += c0 * a0.w + c1 * a1.w + c2 * a2.w + c3 * a3.w + c4v * a4.w;
    ushort4 ob;
    ob.x = f2h(v.x); ob.y = f2h(v.y); ob.z = f2h(v.z); ob.w = f2h(v.w);
    *(ushort4*)(zh + (size_t)u * DD + l32 * 4) = ob;
}

// ---------------- CSR build ----------------
__global__ __launch_bounds__(1024) void k_scan(
    const int* __restrict__ deg, int* __restrict__ rowptr, int* __restrict__ wp, int N, int total)
{
    __shared__ int sdata[1024];
    int t = threadIdx.x;
    int chunk = (N + 1023) >> 10;
    int start = t * chunk, end = min(start + chunk, N);
    int lsum = 0;
    for (int i = start; i < end; i++) lsum += deg[i];
    sdata[t] = lsum;
    __syncthreads();
    for (int off = 1; off < 1024; off <<= 1) {
        int v = (t >= off) ? sdata[t - off] : 0;
        __syncthreads();
        sdata[t] += v;
        __syncthreads();
    }
    int run = sdata[t] - lsum;
    for (int i = start; i < end; i++) { rowptr[i] = run; wp[i] = run; run += deg[i]; }
    if (t == 0) rowptr[N] = total;
}

__global__ __launch_bounds__(256) void k_fill(
    const int* __restrict__ ei, int* __restrict__ wp, int2* __restrict__ adjpair, int E)
{
    int e = blockIdx.x * 256 + threadIdx.x;
    if (e >= E) return;
    int s = ei[e], d = ei[E + e];
    int ps = atomicAdd(&wp[s], 1);
    int2 v1; v1.x = d; v1.y = e;
    adjpair[ps] = v1;
    int pd = atomicAdd(&wp[d], 1);
    int2 v2; v2.x = s; v2.y = e;
    adjpair[pd] = v2;
}

// ---------------- wavelet step: fp16 in -> fp16 out (into comb chunk, stride 512) ----
// 32-lane group per node; 16 lanes per row (16 B/lane uint4 = 8 fp16);
// the two 16-lane halves process 2 neighbor rows concurrently; shfl_xor(16) merges.
// Halves the VMEM instruction count vs 8 B/lane x 32 lanes.
template<int IN_STRIDE>
__global__ __launch_bounds__(256) void k_wav(
    const int* __restrict__ rowptr, const int2* __restrict__ adjpair,
    const unsigned short* __restrict__ yin,
    unsigned short* __restrict__ yout,
    float halfinvnorm, int N)
{
    int g    = threadIdx.x >> 5;
    int l    = threadIdx.x & 31;
    int half = l >> 4;       // which neighbor of the pair
    int seg  = l & 15;       // 16B segment of the row
    int u = blockIdx.x * 8 + g;
    if (u >= N) return;
    int beg = rowptr[u], end = rowptr[u + 1];
    float s[8] = {0.f, 0.f, 0.f, 0.f, 0.f, 0.f, 0.f, 0.f};
    int j = beg;
    for (; j + 1 < end; j += 2) {
        int n = adjpair[j + half].x;
        union { uint4 u4; unsigned short us[8]; } cv;
        cv.u4 = *(const uint4*)(yin + (size_t)n * IN_STRIDE + seg * 8);
#pragma unroll
        for (int k = 0; k < 8; k++) s[k] += h2f(cv.us[k]);
    }
    if (j < end && half == 0) {
        int n = adjpair[j].x;
        union { uint4 u4; unsigned short us[8]; } cv;
        cv.u4 = *(const uint4*)(yin + (size_t)n * IN_STRIDE + seg * 8);
#pragma unroll
        for (int k = 0; k < 8; k++) s[k] += h2f(cv.us[k]);
    }
#pragma unroll
    for (int k = 0; k < 8; k++) s[k] += __shfl_xor(s[k], 16, 64);
    if (half == 0) {
        union { uint4 u4; unsigned short us[8]; } sv;
        sv.u4 = *(const uint4*)(yin + (size_t)u * IN_STRIDE + seg * 8);
        union { uint4 u4; unsigned short us[8]; } ov;
#pragma unroll
        for (int k = 0; k < 8; k++)
            ov.us[k] = f2h(0.5f * h2f(sv.us[k]) + halfinvnorm * s[k]);
        *(uint4*)(yout + (size_t)u * 512 + seg * 8) = ov.u4;
    }
}

// ---------------- weight conversion (transposed, fp16) — merged ----------------
__global__ __launch_bounds__(256) void k_cvtw(
    const float* __restrict__ w1, const float* __restrict__ scales,
    const float* __restrict__ w2,
    unsigned short* __restrict__ w1t, unsigned short* __restrict__ w2t)
{
    int t = blockIdx.x * 256 + threadIdx.x;
    if (t < 512 * 256) {
        int k = t >> 8, n = t & 255;
        w1t[n * 512 + k] = f2h(w1[t] * scales[k >> 7]);
    } else {
        int t2 = t - 512 * 256;
        if (t2 < 256 * 128) {
            int k = t2 >> 7, n = t2 & 127;
            w2t[n * 256 + k] = f2h(w2[t2]);
        }
    }
}

// ---------------- MFMA GEMM (fp16): out[N,NOUT] = A[N,K] @ Bt[NOUT,K]^T + bias ----------------
template<int K, bool RELU_F16>
__global__ __launch_bounds__(256) void k_gemm(
    const unsigned short* __restrict__ A, const unsigned short* __restrict__ Bt,
    const float* __restrict__ bias, void* __restrict__ outp, int N, int NOUT)
{
    __shared__ short sA[128][40];
    __shared__ short sB[64][40];
    int tid = threadIdx.x;
    int r0 = blockIdx.x * 128;
    int n0 = blockIdx.y * 64;
    int lane = tid & 63;
    int w = tid >> 6;
    int quad = lane >> 4;
    int lrow = lane & 15;

    f32x4 acc[2][4];
#pragma unroll
    for (int s = 0; s < 2; s++)
#pragma unroll
        for (int t = 0; t < 4; t++) acc[s][t] = (f32x4){0.f, 0.f, 0.f, 0.f};

    for (int k0 = 0; k0 < K; k0 += 32) {
#pragma unroll
        for (int i = 0; i < 2; i++) {
            int c = tid + i * 256;
            int row = c >> 2, col = (c & 3) * 8;
            ushort4 v2[2];
            if (r0 + row < N) {
                const uint4 g = *(const uint4*)(A + (size_t)(r0 + row) * K + k0 + col);
                *(uint4*)v2 = g;
            } else {
                v2[0] = (ushort4){0,0,0,0}; v2[1] = (ushort4){0,0,0,0};
            }
            *(uint4*)&sA[row][col] = *(uint4*)v2;
        }
        {
            int row = tid >> 2, col = (tid & 3) * 8;
            const uint4 g = *(const uint4*)(Bt + (size_t)(n0 + row) * K + k0 + col);
            *(uint4*)&sB[row][col] = g;
        }
        __syncthreads();
        half8 afr[2], bfr[4];
#pragma unroll
        for (int s = 0; s < 2; s++)
            afr[s] = *(const half8*)&sA[w * 32 + s * 16 + lrow][quad * 8];
#pragma unroll
        for (int t = 0; t < 4; t++)
            bfr[t] = *(const half8*)&sB[t * 16 + lrow][quad * 8];
#pragma unroll
        for (int s = 0; s < 2; s++)
#pragma unroll
            for (int t = 0; t < 4; t++)
                acc[s][t] = __builtin_amdgcn_mfma_f32_16x16x32_f16(afr[s], bfr[t], acc[s][t], 0, 0, 0);
        __syncthreads();
    }
#pragma unroll
    for (int s = 0; s < 2; s++) {
#pragma unroll
        for (int t = 0; t < 4; t++) {
            int col = n0 + t * 16 + lrow;
            float bb = bias[col];
#pragma unroll
            for (int r = 0; r < 4; r++) {
                int row = r0 + w * 32 + s * 16 + quad * 4 + r;
                if (row < N) {
                    float v = acc[s][t][r] + bb;
                    if (RELU_F16) {
                        ((unsigned short*)outp)[(size_t)row * NOUT + col] = f2h(fmaxf(v, 0.f));
                    } else {
                        // final output: streaming, never re-read (scalar float — legal for the builtin)
                        __builtin_nontemporal_store(v, (float*)outp + (size_t)row * NOUT + col);
                    }
                }
            }
        }
    }
}

extern "C" void kernel_launch(void* const* d_in, const int* in_sizes, int n_in,
                              void* d_out, int out_size, void* d_ws, size_t ws_size,
                              hipStream_t stream)
{
    const float* x       = (const float*)d_in[0];
    const int*   ei      = (const int*)d_in[1];
    const float* nanchor = (const float*)d_in[2];
    const float* naw     = (const float*)d_in[3];
    const float* nab     = (const float*)d_in[4];
    const float* eanchor = (const float*)d_in[5];
    const float* eww     = (const float*)d_in[6];
    const float* ewb     = (const float*)d_in[7];
    const float* scales  = (const float*)d_in[8];
    const float* w1      = (const float*)d_in[9];
    const float* b1      = (const float*)d_in[10];
    const float* w2      = (const float*)d_in[11];
    const float* b2      = (const float*)d_in[12];

    int N = in_sizes[0] / DD;
    int E = in_sizes[1] / 2;
    float norm = (float)((double)E / (double)N + 1e-6);
    float hin = 0.5f / norm;

    char* wsb = (char*)d_ws;
    size_t off = 0;
    auto alloc = [&](size_t b) -> char* {
        char* p = wsb + off;
        off += (b + 255) & ~(size_t)255;
        return p;
    };
    float* node_x = (float*)alloc((size_t)N * DD * 4);
    float* p1     = (float*)alloc((size_t)N * 8 * 4);
    float* p2     = (float*)alloc((size_t)N * 8 * 4);
    unsigned short* zh      = (unsigned short*)alloc((size_t)N * DD * 2);
    unsigned short* comb_h  = (unsigned short*)alloc((size_t)N * 512 * 2);
    unsigned short* h_h     = (unsigned short*)alloc((size_t)N * 256 * 2);
    unsigned short* w1t     = (unsigned short*)alloc((size_t)512 * 256 * 2);
    unsigned short* w2t     = (unsigned short*)alloc((size_t)256 * 128 * 2);
    int*   deg    = (int*)alloc((size_t)N * 4);
    int*   rowptr = (int*)alloc((size_t)(N + 1) * 4);
    int*   wp     = (int*)alloc((size_t)N * 4);
    int2*  adjpair= (int2*)alloc((size_t)2 * E * 8);
    float* bes    = (float*)alloc((size_t)E * 32);

    float* out_final   = (float*)d_out;
    float* out_eprompt = out_final + (size_t)N * DD;

    k_cvtw<<<(512 * 256 + 256 * 128 + 255) / 256, 256, 0, stream>>>(w1, scales, w2, w1t, w2t);

    k_node_pre<<<(N + 3) / 4, 256, 0, stream>>>(x, naw, nab, nanchor, eww, node_x, p1, p2, deg, N);
    k_edge<<<(E + 255) / 256, 256, 0, stream>>>(ei, p1, p2, ewb, eanchor, out_eprompt, bes, deg, E);
    k_scan<<<1, 1024, 0, stream>>>(deg, rowptr, wp, N, 2 * E);
    k_fill<<<(E + 255) / 256, 256, 0, stream>>>(ei, wp, adjpair, E);
    k_z<<<(N + 7) / 8, 256, 0, stream>>>(rowptr, adjpair, bes, eanchor, node_x, zh, N);

    // 4 chained wavelet steps, fully fp16: zh -> comb chunk0 -> chunk1 -> chunk2 -> chunk3
    k_wav<DD><<<(N + 7) / 8, 256, 0, stream>>>(rowptr, adjpair, zh, comb_h + 0, hin, N);
    k_wav<512><<<(N + 7) / 8, 256, 0, stream>>>(rowptr, adjpair, comb_h + 0,   comb_h + 128, hin, N);
    k_wav<512><<<(N + 7) / 8, 256, 0, stream>>>(rowptr, adjpair, comb_h + 128, comb_h + 256, hin, N);
    k_wav<512><<<(N + 7) / 8, 256, 0, stream>>>(rowptr, adjpair, comb_h + 256, comb_h + 384, hin, N);

    dim3 g1((N + 127) / 128, 4);
    k_gemm<512, true><<<g1, 256, 0, stream>>>(comb_h, w1t, b1, h_h, N, 256);
    dim3 g2((N + 127) / 128, 2);
    k_gemm<256, false><<<g2, 256, 0, stream>>>(h_h, w2t, b2, out_final, N, 128);
}

// Round 8
// 828.072 us; speedup vs baseline: 1.7111x; 1.1674x over previous
//
#include <hip/hip_runtime.h>
#include <hip/hip_bf16.h>

#define DD 128
#define AA 5

typedef short short8 __attribute__((ext_vector_type(8)));
typedef _Float16 half8 __attribute__((ext_vector_type(8)));
typedef float f32x4 __attribute__((ext_vector_type(4)));

static __device__ __forceinline__ unsigned short f2h(float f) {
    union { _Float16 h; unsigned short u; } v;
    v.h = (_Float16)f;
    return v.u;
}
static __device__ __forceinline__ float h2f(unsigned short u) {
    union { unsigned short u; _Float16 h; } v;
    v.u = u;
    return (float)v.h;
}

// ---------------- node precompute: node_x, p1, p2 (+ deg clear) ----------------
__global__ __launch_bounds__(256) void k_node_pre(
    const float* __restrict__ x, const float* __restrict__ naw, const float* __restrict__ nab,
    const float* __restrict__ nanchor, const float* __restrict__ eww,
    float* __restrict__ node_x, float* __restrict__ p1, float* __restrict__ p2,
    int* __restrict__ deg, int N)
{
    // fused deg clear (replaces hipMemsetAsync)
    int cu = blockIdx.x * 4 + threadIdx.x;
    if (threadIdx.x < 4 && cu < N) deg[cu] = 0;

    int wave = threadIdx.x >> 6;
    int lane = threadIdx.x & 63;
    int u = blockIdx.x * 4 + wave;
    if (u >= N) return;
    int d0 = lane * 2;
    float2 xv = *(const float2*)(x + (size_t)u * DD + d0);
    float nl[AA], a1[AA], a2[AA];
#pragma unroll
    for (int a = 0; a < AA; a++) {
        nl[a] = xv.x * naw[d0 * AA + a] + xv.y * naw[(d0 + 1) * AA + a];
        a1[a] = xv.x * eww[d0 * AA + a] + xv.y * eww[(d0 + 1) * AA + a];
        a2[a] = xv.x * eww[(DD + d0) * AA + a] + xv.y * eww[(DD + d0 + 1) * AA + a];
    }
#pragma unroll
    for (int off = 32; off >= 1; off >>= 1) {
#pragma unroll
        for (int a = 0; a < AA; a++) {
            nl[a] += __shfl_xor(nl[a], off, 64);
            a1[a] += __shfl_xor(a1[a], off, 64);
            a2[a] += __shfl_xor(a2[a], off, 64);
        }
    }
    float m = -1e30f;
#pragma unroll
    for (int a = 0; a < AA; a++) { nl[a] += nab[a]; m = fmaxf(m, nl[a]); }
    float ssum = 0.f;
#pragma unroll
    for (int a = 0; a < AA; a++) { nl[a] = __expf(nl[a] - m); ssum += nl[a]; }
    float inv = 1.0f / ssum;
    float2 o = xv;
#pragma unroll
    for (int a = 0; a < AA; a++) {
        float wgt = nl[a] * inv;
        o.x += wgt * nanchor[a * DD + d0];
        o.y += wgt * nanchor[a * DD + d0 + 1];
    }
    *(float2*)(node_x + (size_t)u * DD + d0) = o;
    if (lane == 0) {
#pragma unroll
        for (int a = 0; a < AA; a++) { p1[u * 8 + a] = a1[a]; p2[u * 8 + a] = a2[a]; }
    }
}

// ---- edge kernel: softmax coeffs -> packed 32B record + CSR rank capture ----
// deg atomicAdd now RETURNS the per-node local rank; stored per edge so k_fill
// needs no atomics at all.
__global__ __launch_bounds__(256) void k_edge(
    const int* __restrict__ ei, const float* __restrict__ p1, const float* __restrict__ p2,
    const float* __restrict__ ewb, const float* __restrict__ eanchor,
    float* __restrict__ eprompt, float* __restrict__ bes,
    int* __restrict__ deg, unsigned short* __restrict__ rr, int E)
{
    __shared__ float be_sh[256][6];
    __shared__ float anc[AA][DD];
    int tid = threadIdx.x;
    for (int i = tid; i < AA * DD; i += 256) anc[i / DD][i % DD] = eanchor[i];
    int e0 = blockIdx.x * 256;
    int e = e0 + tid;
    if (e < E) {
        int s = ei[e], d = ei[E + e];
        int rs = atomicAdd(&deg[s], 1);
        int rd = atomicAdd(&deg[d], 1);
        float l[AA];
        float4 q1 = *(const float4*)(p1 + (size_t)s * 8);
        float  q1e = p1[(size_t)s * 8 + 4];
        float4 q2 = *(const float4*)(p2 + (size_t)d * 8);
        float  q2e = p2[(size_t)d * 8 + 4];
        l[0] = q1.x + q2.x; l[1] = q1.y + q2.y; l[2] = q1.z + q2.z; l[3] = q1.w + q2.w; l[4] = q1e + q2e;
        float m = -1e30f;
#pragma unroll
        for (int a = 0; a < AA; a++) {
            l[a] += ewb[a];
            l[a] = l[a] >= 0.f ? l[a] : 0.01f * l[a];
            m = fmaxf(m, l[a]);
        }
        float ssum = 0.f;
#pragma unroll
        for (int a = 0; a < AA; a++) { l[a] = __expf(l[a] - m); ssum += l[a]; }
        float inv = 1.f / ssum;
#pragma unroll
        for (int a = 0; a < AA; a++) {
            float b = l[a] * inv;
            be_sh[tid][a] = b;
        }
        // packed 32B record: coefficients for this edge live in ONE cache line
        float4 w;
        w.x = be_sh[tid][0]; w.y = be_sh[tid][1]; w.z = be_sh[tid][2]; w.w = be_sh[tid][3];
        *(float4*)(bes + (size_t)e * 8) = w;
        bes[(size_t)e * 8 + 4] = be_sh[tid][4];
        ushort2 rv;
        rv.x = (unsigned short)rs; rv.y = (unsigned short)rd;
        *(ushort2*)(rr + 2 * (size_t)e) = rv;
    }
    __syncthreads();
    int c4 = tid & 31;
    int r  = tid >> 5;
    int nvalid = min(256, E - e0);
    for (int j = r; j < nvalid; j += 8) {
        f32x4 v = {0.f, 0.f, 0.f, 0.f};
#pragma unroll
        for (int a = 0; a < AA; a++) {
            float b = be_sh[j][a];
            v.x += b * anc[a][c4 * 4 + 0];
            v.y += b * anc[a][c4 * 4 + 1];
            v.z += b * anc[a][c4 * 4 + 2];
            v.w += b * anc[a][c4 * 4 + 3];
        }
        // streaming output, never re-read: keep it out of L2/L3
        __builtin_nontemporal_store(v, (f32x4*)(eprompt + (size_t)(e0 + j) * DD + c4 * 4));
    }
}

// ---------------- z = node_x + (gathered coef) @ edge_anchor -> fp16 zh ----------------
__global__ __launch_bounds__(256) void k_z(
    const int* __restrict__ rowptr, const int2* __restrict__ adjpair,
    const float* __restrict__ bes,
    const float* __restrict__ eanchor, const float* __restrict__ node_x,
    unsigned short* __restrict__ zh, int N)
{
    int tid = threadIdx.x;
    int l32 = tid & 31;
    int u = blockIdx.x * 8 + (tid >> 5);
    if (u >= N) return;
    int beg = rowptr[u], end = rowptr[u + 1];
    float c0 = 0.f, c1 = 0.f, c2 = 0.f, c3 = 0.f, c4v = 0.f;
    for (int j = beg + l32; j < end; j += 32) {
        int e = adjpair[j].y;
        float4 v = *(const float4*)(bes + (size_t)e * 8);
        c0 += v.x; c1 += v.y; c2 += v.z; c3 += v.w;
        c4v += bes[(size_t)e * 8 + 4];
    }
#pragma unroll
    for (int off = 16; off >= 1; off >>= 1) {
        c0 += __shfl_xor(c0, off, 64);
        c1 += __shfl_xor(c1, off, 64);
        c2 += __shfl_xor(c2, off, 64);
        c3 += __shfl_xor(c3, off, 64);
        c4v += __shfl_xor(c4v, off, 64);
    }
    float4 v = *(const float4*)(node_x + (size_t)u * DD + l32 * 4);
    const float4 a0 = *(const float4*)(eanchor + 0 * DD + l32 * 4);
    const float4 a1 = *(const float4*)(eanchor + 1 * DD + l32 * 4);
    const float4 a2 = *(const float4*)(eanchor + 2 * DD + l32 * 4);
    const float4 a3 = *(const float4*)(eanchor + 3 * DD + l32 * 4);
    const float4 a4 = *(const float4*)(eanchor + 4 * DD + l32 * 4);
    v.x += c0 * a0.x + c1 * a1.x + c2 * a2.x + c3 * a3.x + c4v * a4.x;
    v.y += c0 * a0.y + c1 * a1.y + c2 * a2.y + c3 * a3.y + c4v * a4.y;
    v.z += c0 * a0.z + c1 * a1.z + c2 * a2.z + c3 * a3.z + c4v * a4.z;
    v.w += c0 * a0.w + c1 * a1.w + c2 * a2.w + c3 * a3.w + c4v * a4.w;
    ushort4 ob;
    ob.x = f2h(v.x); ob.y = f2h(v.y); ob.z = f2h(v.z); ob.w = f2h(v.w);
    *(ushort4*)(zh + (size_t)u * DD + l32 * 4) = ob;
}

// ---------------- CSR build ----------------
__global__ __launch_bounds__(1024) void k_scan(
    const int* __restrict__ deg, int* __restrict__ rowptr, int N, int total)
{
    __shared__ int sdata[1024];
    int t = threadIdx.x;
    int chunk = (N + 1023) >> 10;
    int start = t * chunk, end = min(start + chunk, N);
    int lsum = 0;
    for (int i = start; i < end; i++) lsum += deg[i];
    sdata[t] = lsum;
    __syncthreads();
    for (int off = 1; off < 1024; off <<= 1) {
        int v = (t >= off) ? sdata[t - off] : 0;
        __syncthreads();
        sdata[t] += v;
        __syncthreads();
    }
    int run = sdata[t] - lsum;
    for (int i = start; i < end; i++) { rowptr[i] = run; run += deg[i]; }
    if (t == 0) rowptr[N] = total;
}

// atomic-free fill: slot = rowptr[node] + captured rank
__global__ __launch_bounds__(256) void k_fill(
    const int* __restrict__ ei, const int* __restrict__ rowptr,
    const unsigned short* __restrict__ rr, int2* __restrict__ adjpair, int E)
{
    int e = blockIdx.x * 256 + threadIdx.x;
    if (e >= E) return;
    int s = ei[e], d = ei[E + e];
    ushort2 r = *(const ushort2*)(rr + 2 * (size_t)e);
    int2 v1; v1.x = d; v1.y = e;
    adjpair[rowptr[s] + r.x] = v1;
    int2 v2; v2.x = s; v2.y = e;
    adjpair[rowptr[d] + r.y] = v2;
}

// ---------------- wavelet step: fp16 in -> fp16 out (into comb chunk, stride 512) ----
// 32-lane group per node; 16 lanes per row (16B/lane = 8 fp16).
// 4 neighbors per iteration: each lane loads ONE int4 (2 adjacency pairs) and
// processes 2 rows; halves merge via shfl_xor(16).
template<int IN_STRIDE>
__global__ __launch_bounds__(256) void k_wav(
    const int* __restrict__ rowptr, const int2* __restrict__ adjpair,
    const unsigned short* __restrict__ yin,
    unsigned short* __restrict__ yout,
    float halfinvnorm, int N)
{
    int g    = threadIdx.x >> 5;
    int l    = threadIdx.x & 31;
    int half = l >> 4;       // which 2-neighbor subset of the 4
    int seg  = l & 15;       // 16B segment of the row
    int u = blockIdx.x * 8 + g;
    if (u >= N) return;
    int beg = rowptr[u], end = rowptr[u + 1];
    float s[8] = {0.f, 0.f, 0.f, 0.f, 0.f, 0.f, 0.f, 0.f};
    int j = beg;
    for (; j + 3 < end; j += 4) {
        // lane's int4 covers adjpair[j+2*half] and adjpair[j+2*half+1]
        const int4 q = *(const int4*)(adjpair + j + 2 * half);
        int na = q.x, nb = q.z;
        union { uint4 u4; unsigned short us[8]; } ca, cb;
        ca.u4 = *(const uint4*)(yin + (size_t)na * IN_STRIDE + seg * 8);
        cb.u4 = *(const uint4*)(yin + (size_t)nb * IN_STRIDE + seg * 8);
#pragma unroll
        for (int k = 0; k < 8; k++) s[k] += h2f(ca.us[k]);
#pragma unroll
        for (int k = 0; k < 8; k++) s[k] += h2f(cb.us[k]);
    }
    for (; j + 1 < end; j += 2) {
        int n = adjpair[j + half].x;
        union { uint4 u4; unsigned short us[8]; } cv;
        cv.u4 = *(const uint4*)(yin + (size_t)n * IN_STRIDE + seg * 8);
#pragma unroll
        for (int k = 0; k < 8; k++) s[k] += h2f(cv.us[k]);
    }
    if (j < end && half == 0) {
        int n = adjpair[j].x;
        union { uint4 u4; unsigned short us[8]; } cv;
        cv.u4 = *(const uint4*)(yin + (size_t)n * IN_STRIDE + seg * 8);
#pragma unroll
        for (int k = 0; k < 8; k++) s[k] += h2f(cv.us[k]);
    }
#pragma unroll
    for (int k = 0; k < 8; k++) s[k] += __shfl_xor(s[k], 16, 64);
    if (half == 0) {
        union { uint4 u4; unsigned short us[8]; } sv;
        sv.u4 = *(const uint4*)(yin + (size_t)u * IN_STRIDE + seg * 8);
        union { uint4 u4; unsigned short us[8]; } ov;
#pragma unroll
        for (int k = 0; k < 8; k++)
            ov.us[k] = f2h(0.5f * h2f(sv.us[k]) + halfinvnorm * s[k]);
        *(uint4*)(yout + (size_t)u * 512 + seg * 8) = ov.u4;
    }
}

// ---------------- weight conversion (transposed, fp16) — merged ----------------
__global__ __launch_bounds__(256) void k_cvtw(
    const float* __restrict__ w1, const float* __restrict__ scales,
    const float* __restrict__ w2,
    unsigned short* __restrict__ w1t, unsigned short* __restrict__ w2t)
{
    int t = blockIdx.x * 256 + threadIdx.x;
    if (t < 512 * 256) {
        int k = t >> 8, n = t & 255;
        w1t[n * 512 + k] = f2h(w1[t] * scales[k >> 7]);
    } else {
        int t2 = t - 512 * 256;
        if (t2 < 256 * 128) {
            int k = t2 >> 7, n = t2 & 127;
            w2t[n * 256 + k] = f2h(w2[t2]);
        }
    }
}

// ---------------- MFMA GEMM (fp16): out[N,NOUT] = A[N,K] @ Bt[NOUT,K]^T + bias ----------------
template<int K, bool RELU_F16>
__global__ __launch_bounds__(256) void k_gemm(
    const unsigned short* __restrict__ A, const unsigned short* __restrict__ Bt,
    const float* __restrict__ bias, void* __restrict__ outp, int N, int NOUT)
{
    __shared__ short sA[128][40];
    __shared__ short sB[64][40];
    int tid = threadIdx.x;
    int r0 = blockIdx.x * 128;
    int n0 = blockIdx.y * 64;
    int lane = tid & 63;
    int w = tid >> 6;
    int quad = lane >> 4;
    int lrow = lane & 15;

    f32x4 acc[2][4];
#pragma unroll
    for (int s = 0; s < 2; s++)
#pragma unroll
        for (int t = 0; t < 4; t++) acc[s][t] = (f32x4){0.f, 0.f, 0.f, 0.f};

    for (int k0 = 0; k0 < K; k0 += 32) {
#pragma unroll
        for (int i = 0; i < 2; i++) {
            int c = tid + i * 256;
            int row = c >> 2, col = (c & 3) * 8;
            ushort4 v2[2];
            if (r0 + row < N) {
                const uint4 g = *(const uint4*)(A + (size_t)(r0 + row) * K + k0 + col);
                *(uint4*)v2 = g;
            } else {
                v2[0] = (ushort4){0,0,0,0}; v2[1] = (ushort4){0,0,0,0};
            }
            *(uint4*)&sA[row][col] = *(uint4*)v2;
        }
        {
            int row = tid >> 2, col = (tid & 3) * 8;
            const uint4 g = *(const uint4*)(Bt + (size_t)(n0 + row) * K + k0 + col);
            *(uint4*)&sB[row][col] = g;
        }
        __syncthreads();
        half8 afr[2], bfr[4];
#pragma unroll
        for (int s = 0; s < 2; s++)
            afr[s] = *(const half8*)&sA[w * 32 + s * 16 + lrow][quad * 8];
#pragma unroll
        for (int t = 0; t < 4; t++)
            bfr[t] = *(const half8*)&sB[t * 16 + lrow][quad * 8];
#pragma unroll
        for (int s = 0; s < 2; s++)
#pragma unroll
            for (int t = 0; t < 4; t++)
                acc[s][t] = __builtin_amdgcn_mfma_f32_16x16x32_f16(afr[s], bfr[t], acc[s][t], 0, 0, 0);
        __syncthreads();
    }
#pragma unroll
    for (int s = 0; s < 2; s++) {
#pragma unroll
        for (int t = 0; t < 4; t++) {
            int col = n0 + t * 16 + lrow;
            float bb = bias[col];
#pragma unroll
            for (int r = 0; r < 4; r++) {
                int row = r0 + w * 32 + s * 16 + quad * 4 + r;
                if (row < N) {
                    float v = acc[s][t][r] + bb;
                    if (RELU_F16) {
                        ((unsigned short*)outp)[(size_t)row * NOUT + col] = f2h(fmaxf(v, 0.f));
                    } else {
                        // final output: streaming, never re-read (scalar float — legal for the builtin)
                        __builtin_nontemporal_store(v, (float*)outp + (size_t)row * NOUT + col);
                    }
                }
            }
        }
    }
}

extern "C" void kernel_launch(void* const* d_in, const int* in_sizes, int n_in,
                              void* d_out, int out_size, void* d_ws, size_t ws_size,
                              hipStream_t stream)
{
    const float* x       = (const float*)d_in[0];
    const int*   ei      = (const int*)d_in[1];
    const float* nanchor = (const float*)d_in[2];
    const float* naw     = (const float*)d_in[3];
    const float* nab     = (const float*)d_in[4];
    const float* eanchor = (const float*)d_in[5];
    const float* eww     = (const float*)d_in[6];
    const float* ewb     = (const float*)d_in[7];
    const float* scales  = (const float*)d_in[8];
    const float* w1      = (const float*)d_in[9];
    const float* b1      = (const float*)d_in[10];
    const float* w2      = (const float*)d_in[11];
    const float* b2      = (const float*)d_in[12];

    int N = in_sizes[0] / DD;
    int E = in_sizes[1] / 2;
    float norm = (float)((double)E / (double)N + 1e-6);
    float hin = 0.5f / norm;

    char* wsb = (char*)d_ws;
    size_t off = 0;
    auto alloc = [&](size_t b) -> char* {
        char* p = wsb + off;
        off += (b + 255) & ~(size_t)255;
        return p;
    };
    float* node_x = (float*)alloc((size_t)N * DD * 4);
    float* p1     = (float*)alloc((size_t)N * 8 * 4);
    float* p2     = (float*)alloc((size_t)N * 8 * 4);
    unsigned short* zh      = (unsigned short*)alloc((size_t)N * DD * 2);
    unsigned short* comb_h  = (unsigned short*)alloc((size_t)N * 512 * 2);
    unsigned short* h_h     = (unsigned short*)alloc((size_t)N * 256 * 2);
    unsigned short* w1t     = (unsigned short*)alloc((size_t)512 * 256 * 2);
    unsigned short* w2t     = (unsigned short*)alloc((size_t)256 * 128 * 2);
    int*   deg    = (int*)alloc((size_t)N * 4);
    int*   rowptr = (int*)alloc((size_t)(N + 1) * 4);
    int2*  adjpair= (int2*)alloc((size_t)2 * E * 8);
    float* bes    = (float*)alloc((size_t)E * 32);
    unsigned short* rr = (unsigned short*)alloc((size_t)E * 4);

    float* out_final   = (float*)d_out;
    float* out_eprompt = out_final + (size_t)N * DD;

    k_cvtw<<<(512 * 256 + 256 * 128 + 255) / 256, 256, 0, stream>>>(w1, scales, w2, w1t, w2t);

    k_node_pre<<<(N + 3) / 4, 256, 0, stream>>>(x, naw, nab, nanchor, eww, node_x, p1, p2, deg, N);
    k_edge<<<(E + 255) / 256, 256, 0, stream>>>(ei, p1, p2, ewb, eanchor, out_eprompt, bes, deg, rr, E);
    k_scan<<<1, 1024, 0, stream>>>(deg, rowptr, N, 2 * E);
    k_fill<<<(E + 255) / 256, 256, 0, stream>>>(ei, rowptr, rr, adjpair, E);
    k_z<<<(N + 7) / 8, 256, 0, stream>>>(rowptr, adjpair, bes, eanchor, node_x, zh, N);

    // 4 chained wavelet steps, fully fp16: zh -> comb chunk0 -> chunk1 -> chunk2 -> chunk3
    k_wav<DD><<<(N + 7) / 8, 256, 0, stream>>>(rowptr, adjpair, zh, comb_h + 0, hin, N);
    k_wav<512><<<(N + 7) / 8, 256, 0, stream>>>(rowptr, adjpair, comb_h + 0,   comb_h + 128, hin, N);
    k_wav<512><<<(N + 7) / 8, 256, 0, stream>>>(rowptr, adjpair, comb_h + 128, comb_h + 256, hin, N);
    k_wav<512><<<(N + 7) / 8, 256, 0, stream>>>(rowptr, adjpair, comb_h + 256, comb_h + 384, hin, N);

    dim3 g1((N + 127) / 128, 4);
    k_gemm<512, true><<<g1, 256, 0, stream>>>(comb_h, w1t, b1, h_h, N, 256);
    dim3 g2((N + 127) / 128, 2);
    k_gemm<256, false><<<g2, 256, 0, stream>>>(h_h, w2t, b2, out_final, N, 128);
}